// Round 5
// baseline (302.763 us; speedup 1.0000x reference)
//
#include <hip/hip_runtime.h>
#include <math.h>

#define L_SEQ 256
#define TILE 32

__device__ __forceinline__ float silu_f(float x) { return x / (1.f + __expf(-x)); }
// softplus via hw exp2/log2
__device__ __forceinline__ float sp2_f(float x) {
    return log2f(1.f + exp2f(x * 1.44269504f)) * 0.69314718f;
}

// ---- prep: fold exp_w@in_proj_w -> weff/beff ; transpose x_proj_w -> [36][132] f32 ----
__global__ __launch_bounds__(256)
void k_prep(const float* __restrict__ exp_w, const float* __restrict__ exp_b,
            const float* __restrict__ in_proj_w, const float* __restrict__ x_proj_w,
            float* __restrict__ weff, float* __restrict__ beff, float* __restrict__ xpwt)
{
    const int t = threadIdx.x;
    float a0 = 0, a1 = 0, a2 = 0, a3 = 0, ab = 0;
    for (int k = 0; k < 64; ++k) {
        float w = in_proj_w[k * 256 + t];
        a0 = fmaf(exp_w[k], w, a0);
        a1 = fmaf(exp_w[64 + k], w, a1);
        a2 = fmaf(exp_w[128 + k], w, a2);
        a3 = fmaf(exp_w[192 + k], w, a3);
        ab = fmaf(exp_b[k], w, ab);
    }
    weff[t] = a0; weff[256 + t] = a1; weff[512 + t] = a2; weff[768 + t] = a3;
    beff[t] = ab;
    for (int i = t; i < 128 * 36; i += 256) {
        int k = i / 36, j = i - k * 36;
        xpwt[j * 132 + k] = x_proj_w[i];
    }
}

// ---- segmented fused Mamba: grid = B * nseg, one 64-step segment per block ----
__global__ __launch_bounds__(256, 4)
void mamba_seg(const float* __restrict__ reads,
               const float* __restrict__ weff, const float* __restrict__ beff,
               const float* __restrict__ xpwt,
               const float* __restrict__ conv_w, const float* __restrict__ conv_b,
               const float* __restrict__ dt_w, const float* __restrict__ dt_b,
               const float* __restrict__ A_log, const float* __restrict__ D_skip,
               float* __restrict__ Qg, float* __restrict__ Pg, float* __restrict__ Kg,
               float* __restrict__ GS, float* __restrict__ CZ, float* __restrict__ SL,
               int Bn, int seg_shift)
{
    const int nseg = 1 << seg_shift;
    const int ntile = (L_SEQ / TILE) >> seg_shift;
    const int bx = blockIdx.x;
    const int b = bx >> seg_shift;
    const int sidx = bx & (nseg - 1);
    const int seg0 = sidx * ntile * TILE;
    const int t = threadIdx.x;
    const int dA = t & 127, lh = t >> 7;   // phase A mapping (channel, l-half)

    __shared__ __align__(16) float    RD[2][36 * 4];   // reads rows (+3 halo), dbuf
    __shared__ __align__(16) float    XCf[TILE * 132]; // conv output, f32, padded
    __shared__ __align__(16) float    BC[TILE * 32];   // B(16)|C(16) per step
    __shared__ __align__(16) float    DT4[TILE * 4];   // dt-rank outputs
    __shared__ _Float16               ZS[TILE * 128];  // silu(z), fp16

    // phase A weights (xm col dA, z col 128+dA)
    const float wx0 = weff[dA], wx1 = weff[256 + dA], wx2 = weff[512 + dA], wx3 = weff[768 + dA];
    const float bxc = beff[dA];
    const float wz0 = weff[128 + dA], wz1 = weff[384 + dA], wz2 = weff[640 + dA], wz3 = weff[896 + dA];
    const float bzc = beff[128 + dA];
    const float4 cw = ((const float4*)conv_w)[dA];
    const float cb = conv_b[dA];
    // phase E per-channel weights (t < 128 scans channel t)
    const float dw0 = dt_w[dA], dw1 = dt_w[128 + dA], dw2 = dt_w[256 + dA], dw3 = dt_w[384 + dA];
    const float db = dt_b[dA];
    const float dskip = D_skip[dA];
    bool structured = true;
#pragma unroll
    for (int n = 0; n < 16; ++n) {
        float a = -__expf(A_log[dA * 16 + n]);
        structured = structured && (fabsf(a + (float)(n + 1)) < 1e-3f);
    }

    const float4* rdv = (const float4*)(reads + (size_t)b * L_SEQ * 4);
    if (t < 35) {
        int row = seg0 - 3 + t;
        float4 v = make_float4(0.f, 0.f, 0.f, 0.f);
        if (row >= 0) v = rdv[row];
        ((float4*)RD[0])[t] = v;
    }

    float h[16], P[16], K[16];
    float gsum = 0.f, zs_last = 0.f, xc_last = 0.f;
#pragma unroll
    for (int n = 0; n < 16; ++n) { h[n] = 0.f; P[n] = 1.f; K[n] = 0.f; }

    __syncthreads();

    for (int tile = 0; tile < ntile; ++tile) {
        const int cur = tile & 1;
        const int l_off = seg0 + tile * TILE;
        const float4* RDc = (const float4*)RD[cur];

        // ---- phase A: xm rolling window + conv + silu -> XCf ; z + silu -> ZS ----
        {
            const int lb = lh * 16;
            float x0, x1, x2;
            {
                float4 rv = RDc[lb + 0];
                x0 = bxc + rv.x * wx0 + rv.y * wx1 + rv.z * wx2 + rv.w * wx3;
                if (l_off + lb - 3 < 0) x0 = 0.f;
                rv = RDc[lb + 1];
                x1 = bxc + rv.x * wx0 + rv.y * wx1 + rv.z * wx2 + rv.w * wx3;
                if (l_off + lb - 2 < 0) x1 = 0.f;
                rv = RDc[lb + 2];
                x2 = bxc + rv.x * wx0 + rv.y * wx1 + rv.z * wx2 + rv.w * wx3;
                if (l_off + lb - 1 < 0) x2 = 0.f;
            }
#pragma unroll
            for (int i = 0; i < 16; ++i) {
                float4 rv = RDc[lb + 3 + i];
                float xn = bxc + rv.x * wx0 + rv.y * wx1 + rv.z * wx2 + rv.w * wx3;
                float s = cb + x0 * cw.x + x1 * cw.y + x2 * cw.z + xn * cw.w;
                XCf[(lb + i) * 132 + dA] = silu_f(s);
                float z = bzc + rv.x * wz0 + rv.y * wz1 + rv.z * wz2 + rv.w * wz3;
                ZS[(lb + i) * 128 + dA] = (_Float16)silu_f(z);
                x0 = x1; x1 = x2; x2 = xn;
            }
        }
        __syncthreads();

        // ---- phase C: x_proj (32 x 36) -> DT4|BC ; prefetch next RD ----
        if (t < 35 && tile + 1 < ntile) {
            int row = l_off + TILE - 3 + t;
            ((float4*)RD[cur ^ 1])[t] = rdv[row];
        }
        for (int task = t; task < 288; task += 256) {
            const int lg = task / 18, jg = task - lg * 18;
            const float4* xr0 = (const float4*)&XCf[(2 * lg) * 132];
            const float4* xr1 = (const float4*)&XCf[(2 * lg + 1) * 132];
            const float4* w0p = (const float4*)&xpwt[(2 * jg) * 132];
            const float4* w1p = (const float4*)&xpwt[(2 * jg + 1) * 132];
            float a00 = 0, a01 = 0, a10 = 0, a11 = 0;
#pragma unroll 8
            for (int kq = 0; kq < 32; ++kq) {
                float4 xa = xr0[kq], xb = xr1[kq];
                float4 wa = w0p[kq], wb = w1p[kq];
                a00 = fmaf(xa.x, wa.x, a00); a01 = fmaf(xa.x, wb.x, a01);
                a10 = fmaf(xb.x, wa.x, a10); a11 = fmaf(xb.x, wb.x, a11);
                a00 = fmaf(xa.y, wa.y, a00); a01 = fmaf(xa.y, wb.y, a01);
                a10 = fmaf(xb.y, wa.y, a10); a11 = fmaf(xb.y, wb.y, a11);
                a00 = fmaf(xa.z, wa.z, a00); a01 = fmaf(xa.z, wb.z, a01);
                a10 = fmaf(xb.z, wa.z, a10); a11 = fmaf(xb.z, wb.z, a11);
                a00 = fmaf(xa.w, wa.w, a00); a01 = fmaf(xa.w, wb.w, a01);
                a10 = fmaf(xb.w, wa.w, a10); a11 = fmaf(xb.w, wb.w, a11);
            }
            const int l = 2 * lg, j = 2 * jg;
            if (j < 4) {
                DT4[l * 4 + j] = a00;       DT4[l * 4 + j + 1] = a01;
                DT4[(l + 1) * 4 + j] = a10; DT4[(l + 1) * 4 + j + 1] = a11;
            } else {
                BC[l * 32 + j - 4] = a00;       BC[l * 32 + j - 3] = a01;
                BC[(l + 1) * 32 + j - 4] = a10; BC[(l + 1) * 32 + j - 3] = a11;
            }
        }
        __syncthreads();

        // ---- phase E: serial scan, 1 lane per channel, 16 states in-lane ----
        if (t < 128) {
            for (int l = 0; l < TILE; ++l) {
                float4 dv = *(const float4*)&DT4[l * 4];
                float de = sp2_f(db + dv.x * dw0 + dv.y * dw1 + dv.z * dw2 + dv.w * dw3);
                float zs = (float)ZS[l * 128 + t];
                float xc = XCf[l * 132 + t];
                const float du = de * xc;
                float e[16];
                if (structured) {       // A[n] = -(n+1): e[n] = r^(n+1)
                    const float r = exp2f(de * -1.44269504f);
                    e[0] = r;
                    e[1] = r * r;       e[2] = e[1] * r;    e[3] = e[1] * e[1];
                    e[4] = e[3] * r;    e[5] = e[3] * e[1]; e[6] = e[3] * e[2];
                    e[7] = e[3] * e[3];
                    e[8] = e[7] * r;    e[9] = e[7] * e[1]; e[10] = e[7] * e[2];
                    e[11] = e[7] * e[3]; e[12] = e[7] * e[4]; e[13] = e[7] * e[5];
                    e[14] = e[7] * e[6]; e[15] = e[7] * e[7];
                } else {                 // cold generic path
#pragma unroll
                    for (int n = 0; n < 16; ++n) {
                        float a = -__expf(A_log[t * 16 + n]);
                        e[n] = exp2f(de * a * 1.44269504f);
                    }
                }
                const float4 Bq0 = *(const float4*)&BC[l * 32];
                const float4 Bq1 = *(const float4*)&BC[l * 32 + 4];
                const float4 Bq2 = *(const float4*)&BC[l * 32 + 8];
                const float4 Bq3 = *(const float4*)&BC[l * 32 + 12];
                const float Bv[16] = {Bq0.x, Bq0.y, Bq0.z, Bq0.w, Bq1.x, Bq1.y, Bq1.z, Bq1.w,
                                      Bq2.x, Bq2.y, Bq2.z, Bq2.w, Bq3.x, Bq3.y, Bq3.z, Bq3.w};
                const float4 Cq0 = *(const float4*)&BC[l * 32 + 16];
                const float4 Cq1 = *(const float4*)&BC[l * 32 + 20];
                const float4 Cq2 = *(const float4*)&BC[l * 32 + 24];
                const float4 Cq3 = *(const float4*)&BC[l * 32 + 28];
                const float Cv[16] = {Cq0.x, Cq0.y, Cq0.z, Cq0.w, Cq1.x, Cq1.y, Cq1.z, Cq1.w,
                                      Cq2.x, Cq2.y, Cq2.z, Cq2.w, Cq3.x, Cq3.y, Cq3.z, Cq3.w};
                float y0 = 0.f, y1 = 0.f;
#pragma unroll
                for (int n = 0; n < 8; ++n) {
                    h[n] = fmaf(e[n], h[n], du * Bv[n]);
                    y0 = fmaf(h[n], Cv[n], y0);
                    P[n] *= e[n];
                    K[n] = fmaf(zs, Cv[n] * P[n], K[n]);
                }
#pragma unroll
                for (int n = 8; n < 16; ++n) {
                    h[n] = fmaf(e[n], h[n], du * Bv[n]);
                    y1 = fmaf(h[n], Cv[n], y1);
                    P[n] *= e[n];
                    K[n] = fmaf(zs, Cv[n] * P[n], K[n]);
                }
                gsum += fmaf(xc, dskip, y0 + y1) * zs;
                zs_last = zs; xc_last = xc;
            }
        }
        __syncthreads();
    }

    // ---- segment summary writeout (BC still holds last tile's rows) ----
    if (t < 128) {
        const size_t sb = (size_t)sidx * Bn + b;
#pragma unroll
        for (int n = 0; n < 16; ++n) {
            const size_t o = (sb * 16 + n) * 128 + t;
            Qg[o] = h[n];
            Pg[o] = P[n];
            Kg[o] = K[n];
        }
        GS[sb * 128 + t] = gsum;
        if (sidx == nseg - 1) {
#pragma unroll
            for (int n = 0; n < 16; ++n)
                CZ[((size_t)b * 16 + n) * 128 + t] = zs_last * BC[(TILE - 1) * 32 + 16 + n];
            SL[(size_t)b * 128 + t] = zs_last * xc_last * dskip;
        }
    }
}

// ---- stitch: chain segment summaries, out_proj, fused keys ----
__global__ __launch_bounds__(128)
void stitch(const float* __restrict__ Qg, const float* __restrict__ Pg,
            const float* __restrict__ Kg, const float* __restrict__ GS,
            const float* __restrict__ CZ, const float* __restrict__ SL,
            const float* __restrict__ out_proj_w,
            const float* __restrict__ k_w, const float* __restrict__ k_b,
            float* __restrict__ pooled, float* __restrict__ keysT,
            int Bn, int seg_shift)
{
    const int nseg = 1 << seg_shift;
    const int b = blockIdx.x, d = threadIdx.x;
    __shared__ float gb[256];
    __shared__ float pl[128];

    float h[16];
#pragma unroll
    for (int n = 0; n < 16; ++n) h[n] = 0.f;
    float gsum = 0.f;
    for (int s = 0; s < nseg; ++s) {
        const size_t sb = (size_t)s * Bn + b;
        gsum += GS[sb * 128 + d];
        float corr = 0.f;
#pragma unroll
        for (int n = 0; n < 16; ++n) {
            const size_t o = (sb * 16 + n) * 128 + d;
            corr = fmaf(Kg[o], h[n], corr);        // uses pre-update h
            h[n] = fmaf(Pg[o], h[n], Qg[o]);
        }
        gsum += corr;
    }
    float glast = SL[(size_t)b * 128 + d];
#pragma unroll
    for (int n = 0; n < 16; ++n)
        glast = fmaf(CZ[((size_t)b * 16 + n) * 128 + d], h[n], glast);

    gb[d] = gsum * (1.f / (float)L_SEQ);
    gb[128 + d] = glast;
    __syncthreads();
    {
        const int half = d >> 6, oc = d & 63;
        const float* gbp = &gb[half * 128];
        float s = 0.f;
#pragma unroll 16
        for (int i = 0; i < 128; ++i) s = fmaf(gbp[i], out_proj_w[i * 64 + oc], s);
        pooled[(size_t)b * 128 + d] = s;
        pl[d] = s;
    }
    __syncthreads();
    if (d < 64) {
        float s = k_b[d];
#pragma unroll 16
        for (int i = 0; i < 128; ++i) s = fmaf(pl[i], k_w[i * 64 + d], s);
        keysT[(size_t)d * Bn + b] = s;
    }
}

// ---- qk: per query row, q = pooled[idx] @ q_w + q_b ; out = q @ keysT ----
__global__ __launch_bounds__(256)
void qk_kernel(const float* __restrict__ pooled, const int* __restrict__ idx,
               const float* __restrict__ q_w, const float* __restrict__ q_b,
               const float* __restrict__ keysT, float* __restrict__ out, int B)
{
    int n = blockIdx.x, t = threadIdx.x;
    __shared__ float p_lds[128];
    __shared__ float q_lds[64];
    int bi = idx[n];
    if (t < 128) p_lds[t] = pooled[(size_t)bi * 128 + t];
    __syncthreads();
    if (t < 64) {
        float s = q_b[t];
#pragma unroll
        for (int i = 0; i < 128; ++i) s = fmaf(p_lds[i], q_w[i * 64 + t], s);
        q_lds[t] = s;
    }
    __syncthreads();
    for (int m = t; m < B; m += 256) {
        float acc = 0.f;
#pragma unroll
        for (int i = 0; i < 64; ++i) acc = fmaf(q_lds[i], keysT[(size_t)i * B + m], acc);
        out[(size_t)n * B + m] = acc;
    }
}

// ============================ LAUNCH ============================

extern "C" void kernel_launch(void* const* d_in, const int* in_sizes, int n_in,
                              void* d_out, int out_size, void* d_ws, size_t ws_size,
                              hipStream_t stream)
{
    const float* reads      = (const float*)d_in[0];
    const int*   idx        = (const int*)d_in[1];
    const float* exp_w      = (const float*)d_in[2];
    const float* exp_b      = (const float*)d_in[3];
    const float* in_proj_w  = (const float*)d_in[4];
    const float* conv_w     = (const float*)d_in[5];
    const float* conv_b     = (const float*)d_in[6];
    const float* x_proj_w   = (const float*)d_in[7];
    const float* dt_w       = (const float*)d_in[8];
    const float* dt_b       = (const float*)d_in[9];
    const float* A_log      = (const float*)d_in[10];
    const float* D_skip     = (const float*)d_in[11];
    const float* out_proj_w = (const float*)d_in[12];
    const float* q_w        = (const float*)d_in[13];
    const float* q_b        = (const float*)d_in[14];
    const float* k_w        = (const float*)d_in[15];
    const float* k_b        = (const float*)d_in[16];

    const int B = in_sizes[0] / (L_SEQ * 4);
    const int N = in_sizes[1];

    char* wsb = (char*)d_ws;
    size_t off = 0;
    auto alloc = [&](size_t bytes) {
        size_t o = off;
        off = (off + bytes + 255) & ~(size_t)255;
        return o;
    };

    float* pooled = (float*)(wsb + alloc((size_t)B * 128 * 4));
    float* keysT  = (float*)(wsb + alloc((size_t)B * 64 * 4));
    float* weff   = (float*)(wsb + alloc(1024 * 4));
    float* beff   = (float*)(wsb + alloc(256 * 4));
    float* xpwt   = (float*)(wsb + alloc(36 * 132 * 4));

    auto summ_bytes = [&](int shift) {
        size_t rows = ((size_t)B << shift) * 16 * 128;
        return rows * 4 * 3                       // Qg, Pg, Kg
             + ((size_t)B << shift) * 128 * 4     // GS
             + (size_t)B * 16 * 128 * 4           // CZ
             + (size_t)B * 128 * 4 + 4096;        // SL + align slack
    };
    int seg_shift = 2;
    if (off + summ_bytes(2) > ws_size) seg_shift = 0;   // fallback: unsegmented

    const int nseg = 1 << seg_shift;
    const size_t rows = (size_t)B * nseg * 16 * 128;
    float* Qg = (float*)(wsb + alloc(rows * 4));
    float* Pg = (float*)(wsb + alloc(rows * 4));
    float* Kg = (float*)(wsb + alloc(rows * 4));
    float* GS = (float*)(wsb + alloc((size_t)B * nseg * 128 * 4));
    float* CZ = (float*)(wsb + alloc((size_t)B * 16 * 128 * 4));
    float* SL = (float*)(wsb + alloc((size_t)B * 128 * 4));

    k_prep<<<1, 256, 0, stream>>>(exp_w, exp_b, in_proj_w, x_proj_w, weff, beff, xpwt);
    mamba_seg<<<B * nseg, 256, 0, stream>>>(reads, weff, beff, xpwt, conv_w, conv_b,
                                            dt_w, dt_b, A_log, D_skip,
                                            Qg, Pg, Kg, GS, CZ, SL, B, seg_shift);
    stitch<<<B, 128, 0, stream>>>(Qg, Pg, Kg, GS, CZ, SL, out_proj_w, k_w, k_b,
                                  pooled, keysT, B, seg_shift);
    qk_kernel<<<N, 256, 0, stream>>>(pooled, idx, q_w, q_b, keysT, (float*)d_out, B);
}

// Round 6
// 262.574 us; speedup vs baseline: 1.1531x; 1.1531x over previous
//
#include <hip/hip_runtime.h>
#include <math.h>

#define L_SEQ 256
#define TILE 32

__device__ __forceinline__ float silu_f(float x) { return x / (1.f + __expf(-x)); }
// softplus via hw exp2/log2
__device__ __forceinline__ float sp2_f(float x) {
    return log2f(1.f + exp2f(x * 1.44269504f)) * 0.69314718f;
}

// ---- prep: fold exp_w@in_proj_w -> weff/beff ; transpose x_proj_w -> [36][132] f32 ----
__global__ __launch_bounds__(256)
void k_prep(const float* __restrict__ exp_w, const float* __restrict__ exp_b,
            const float* __restrict__ in_proj_w, const float* __restrict__ x_proj_w,
            float* __restrict__ weff, float* __restrict__ beff, float* __restrict__ xpwt)
{
    const int t = threadIdx.x;
    float a0 = 0, a1 = 0, a2 = 0, a3 = 0, ab = 0;
    for (int k = 0; k < 64; ++k) {
        float w = in_proj_w[k * 256 + t];
        a0 = fmaf(exp_w[k], w, a0);
        a1 = fmaf(exp_w[64 + k], w, a1);
        a2 = fmaf(exp_w[128 + k], w, a2);
        a3 = fmaf(exp_w[192 + k], w, a3);
        ab = fmaf(exp_b[k], w, ab);
    }
    weff[t] = a0; weff[256 + t] = a1; weff[512 + t] = a2; weff[768 + t] = a3;
    beff[t] = ab;
    for (int i = t; i < 128 * 36; i += 256) {
        int k = i / 36, j = i - k * 36;
        xpwt[j * 132 + k] = x_proj_w[i];
    }
}

// ---- segmented fused Mamba: grid = B * nseg, one segment per block ----
__global__ __launch_bounds__(256, 4)
void mamba_seg(const float* __restrict__ reads,
               const float* __restrict__ weff, const float* __restrict__ beff,
               const float* __restrict__ xpwt,
               const float* __restrict__ conv_w, const float* __restrict__ conv_b,
               const float* __restrict__ dt_w, const float* __restrict__ dt_b,
               const float* __restrict__ A_log, const float* __restrict__ D_skip,
               float* __restrict__ Qg, float* __restrict__ Pg, float* __restrict__ Kg,
               float* __restrict__ GS, float* __restrict__ CZ, float* __restrict__ SL,
               int Bn, int seg_shift)
{
    const int nseg = 1 << seg_shift;
    const int ntile = (L_SEQ / TILE) >> seg_shift;
    const int bx = blockIdx.x;
    const int b = bx >> seg_shift;
    const int sidx = bx & (nseg - 1);
    const int seg0 = sidx * ntile * TILE;
    const int t = threadIdx.x;
    const int dA = t & 127, lh = t >> 7;   // phase A/D mapping (channel, l-half)
    const int dd = t >> 1,  g  = t & 1;    // phase E mapping (channel, n-group)

    __shared__ __align__(16) float    RD[2][36 * 4];   // reads rows (+3 halo), dbuf
    __shared__ __align__(16) float    XCf[TILE * 132]; // conv output, f32, padded
    __shared__ __align__(16) float    BC[TILE * 32];   // B(16)|C(16) per step
    __shared__ __align__(16) float    DT4[TILE * 4];   // dt-rank outputs
    __shared__ _Float16               ZS[TILE * 128];  // silu(z), fp16
    __shared__ _Float16               DE[TILE * 128];  // delta, fp16

    // phase A weights (xm col dA, z col 128+dA)
    const float wx0 = weff[dA], wx1 = weff[256 + dA], wx2 = weff[512 + dA], wx3 = weff[768 + dA];
    const float bxc = beff[dA];
    const float wz0 = weff[128 + dA], wz1 = weff[384 + dA], wz2 = weff[640 + dA], wz3 = weff[896 + dA];
    const float bzc = beff[128 + dA];
    const float4 cw = ((const float4*)conv_w)[dA];
    const float cb = conv_b[dA];
    // phase D weights (channel dA)
    const float dw0 = dt_w[dA], dw1 = dt_w[128 + dA], dw2 = dt_w[256 + dA], dw3 = dt_w[384 + dA];
    const float db = dt_b[dA];
    // phase E per-channel params (channel dd, states g*8..g*8+7)
    const float dskip = D_skip[dd];
    bool structured = true;
#pragma unroll
    for (int k = 0; k < 8; ++k) {
        float a = -__expf(A_log[dd * 16 + g * 8 + k]);
        structured = structured && (fabsf(a + (float)(g * 8 + k + 1)) < 1e-3f);
    }

    const float4* rdv = (const float4*)(reads + (size_t)b * L_SEQ * 4);
    if (t < 35) {
        int row = seg0 - 3 + t;
        float4 v = make_float4(0.f, 0.f, 0.f, 0.f);
        if (row >= 0) v = rdv[row];
        ((float4*)RD[0])[t] = v;
    }

    float h[8], P[8], K[8];
    float gsum = 0.f, zs_last = 0.f, xc_last = 0.f;
#pragma unroll
    for (int k = 0; k < 8; ++k) { h[k] = 0.f; P[k] = 1.f; K[k] = 0.f; }

    __syncthreads();

    for (int tile = 0; tile < ntile; ++tile) {
        const int cur = tile & 1;
        const int l_off = seg0 + tile * TILE;
        const float4* RDc = (const float4*)RD[cur];

        // ---- phase A: xm rolling window + conv + silu -> XCf ; z -> silu -> ZS ----
        {
            const int lb = lh * 16;
            float x0, x1, x2;
            {
                float4 rv = RDc[lb + 0];
                x0 = bxc + rv.x * wx0 + rv.y * wx1 + rv.z * wx2 + rv.w * wx3;
                if (l_off + lb - 3 < 0) x0 = 0.f;
                rv = RDc[lb + 1];
                x1 = bxc + rv.x * wx0 + rv.y * wx1 + rv.z * wx2 + rv.w * wx3;
                if (l_off + lb - 2 < 0) x1 = 0.f;
                rv = RDc[lb + 2];
                x2 = bxc + rv.x * wx0 + rv.y * wx1 + rv.z * wx2 + rv.w * wx3;
                if (l_off + lb - 1 < 0) x2 = 0.f;
            }
#pragma unroll
            for (int i = 0; i < 16; ++i) {
                float4 rv = RDc[lb + 3 + i];
                float xn = bxc + rv.x * wx0 + rv.y * wx1 + rv.z * wx2 + rv.w * wx3;
                float s = cb + x0 * cw.x + x1 * cw.y + x2 * cw.z + xn * cw.w;
                XCf[(lb + i) * 132 + dA] = silu_f(s);
                float z = bzc + rv.x * wz0 + rv.y * wz1 + rv.z * wz2 + rv.w * wz3;
                ZS[(lb + i) * 128 + dA] = (_Float16)silu_f(z);
                x0 = x1; x1 = x2; x2 = xn;
            }
        }
        __syncthreads();

        // ---- phase C: x_proj (32 x 36) -> DT4|BC ; prefetch next RD ----
        if (t < 35 && tile + 1 < ntile) {
            int row = l_off + TILE - 3 + t;
            ((float4*)RD[cur ^ 1])[t] = rdv[row];
        }
        for (int task = t; task < 288; task += 256) {
            const int lg = task / 18, jg = task - lg * 18;
            const float4* xr0 = (const float4*)&XCf[(2 * lg) * 132];
            const float4* xr1 = (const float4*)&XCf[(2 * lg + 1) * 132];
            const float4* w0p = (const float4*)&xpwt[(2 * jg) * 132];
            const float4* w1p = (const float4*)&xpwt[(2 * jg + 1) * 132];
            float a00 = 0, a01 = 0, a10 = 0, a11 = 0;
#pragma unroll 8
            for (int kq = 0; kq < 32; ++kq) {
                float4 xa = xr0[kq], xb = xr1[kq];
                float4 wa = w0p[kq], wb = w1p[kq];
                a00 = fmaf(xa.x, wa.x, a00); a01 = fmaf(xa.x, wb.x, a01);
                a10 = fmaf(xb.x, wa.x, a10); a11 = fmaf(xb.x, wb.x, a11);
                a00 = fmaf(xa.y, wa.y, a00); a01 = fmaf(xa.y, wb.y, a01);
                a10 = fmaf(xb.y, wa.y, a10); a11 = fmaf(xb.y, wb.y, a11);
                a00 = fmaf(xa.z, wa.z, a00); a01 = fmaf(xa.z, wb.z, a01);
                a10 = fmaf(xb.z, wa.z, a10); a11 = fmaf(xb.z, wb.z, a11);
                a00 = fmaf(xa.w, wa.w, a00); a01 = fmaf(xa.w, wb.w, a01);
                a10 = fmaf(xb.w, wa.w, a10); a11 = fmaf(xb.w, wb.w, a11);
            }
            const int l = 2 * lg, j = 2 * jg;
            if (j < 4) {
                DT4[l * 4 + j] = a00;       DT4[l * 4 + j + 1] = a01;
                DT4[(l + 1) * 4 + j] = a10; DT4[(l + 1) * 4 + j + 1] = a11;
            } else {
                BC[l * 32 + j - 4] = a00;       BC[l * 32 + j - 3] = a01;
                BC[(l + 1) * 32 + j - 4] = a10; BC[(l + 1) * 32 + j - 3] = a11;
            }
        }
        __syncthreads();

        // ---- phase D: delta = softplus(dt @ dt_w + dt_b) -> DE (parallel) ----
        {
            const int lb = lh * 16;
#pragma unroll
            for (int i = 0; i < 16; ++i) {
                const int l = lb + i;
                float4 dv = *(const float4*)&DT4[l * 4];
                float dtr = db + dv.x * dw0 + dv.y * dw1 + dv.z * dw2 + dv.w * dw3;
                DE[l * 128 + dA] = (_Float16)sp2_f(dtr);
            }
        }
        __syncthreads();

        // ---- phase E: serial scan; 2 lanes per channel, divergence-free ----
        {
            auto scan_loop = [&](bool needpk) {
                for (int l = 0; l < TILE; ++l) {
                    const float de = (float)DE[l * 128 + dd];
                    const float zs = (float)ZS[l * 128 + dd];
                    const float xc = XCf[l * 132 + dd];
                    const float du = de * xc;
                    float e[8];
                    if (structured) {       // A[n] = -(n+1): e[k] = r^(g*8+k+1)
                        const float r = exp2f(de * -1.44269504f);
                        const float p2 = r * r, p3 = p2 * r, p4 = p2 * p2;
                        const float p5 = p4 * r, p6 = p4 * p2, p7 = p4 * p3, p8 = p4 * p4;
                        const float base = g ? p8 : 1.0f;
                        e[0] = r * base;  e[1] = p2 * base; e[2] = p3 * base; e[3] = p4 * base;
                        e[4] = p5 * base; e[5] = p6 * base; e[6] = p7 * base; e[7] = p8 * base;
                    } else {                 // cold generic path
#pragma unroll
                        for (int k = 0; k < 8; ++k) {
                            float a = -__expf(A_log[dd * 16 + g * 8 + k]);
                            e[k] = exp2f(de * a * 1.44269504f);
                        }
                    }
                    const float4 Bq0 = *(const float4*)&BC[l * 32 + g * 8];
                    const float4 Bq1 = *(const float4*)&BC[l * 32 + g * 8 + 4];
                    const float4 Cq0 = *(const float4*)&BC[l * 32 + 16 + g * 8];
                    const float4 Cq1 = *(const float4*)&BC[l * 32 + 16 + g * 8 + 4];
                    const float Bv[8] = {Bq0.x, Bq0.y, Bq0.z, Bq0.w, Bq1.x, Bq1.y, Bq1.z, Bq1.w};
                    const float Cv[8] = {Cq0.x, Cq0.y, Cq0.z, Cq0.w, Cq1.x, Cq1.y, Cq1.z, Cq1.w};
                    float yp = 0.f;
#pragma unroll
                    for (int k = 0; k < 8; ++k) {
                        h[k] = fmaf(e[k], h[k], du * Bv[k]);
                        yp = fmaf(h[k], Cv[k], yp);
                        if (needpk) {
                            P[k] *= e[k];
                            K[k] = fmaf(zs, Cv[k] * P[k], K[k]);
                        }
                    }
                    const float y = yp + __shfl_xor(yp, 1);
                    gsum += fmaf(xc, dskip, y) * zs;
                    zs_last = zs; xc_last = xc;
                }
            };
            if (sidx == 0) scan_loop(false);
            else           scan_loop(true);
        }
        __syncthreads();
    }

    // ---- segment summary writeout (BC still holds last tile's rows) ----
    {
        const size_t sb = (size_t)sidx * Bn + b;
#pragma unroll
        for (int k = 0; k < 8; ++k) {
            const size_t o = (sb * 16 + g * 8 + k) * 128 + dd;
            Qg[o] = h[k];
            if (sidx != 0) { Pg[o] = P[k]; Kg[o] = K[k]; }
        }
        if (g == 0) GS[sb * 128 + dd] = gsum;
        if (sidx == nseg - 1) {
#pragma unroll
            for (int k = 0; k < 8; ++k)
                CZ[((size_t)b * 16 + g * 8 + k) * 128 + dd] = zs_last * BC[(TILE - 1) * 32 + 16 + g * 8 + k];
            if (g == 0) SL[(size_t)b * 128 + dd] = zs_last * xc_last * dskip;
        }
    }
}

// ---- stitch: chain segment summaries, out_proj, fused keys ----
__global__ __launch_bounds__(128)
void stitch(const float* __restrict__ Qg, const float* __restrict__ Pg,
            const float* __restrict__ Kg, const float* __restrict__ GS,
            const float* __restrict__ CZ, const float* __restrict__ SL,
            const float* __restrict__ out_proj_w,
            const float* __restrict__ k_w, const float* __restrict__ k_b,
            float* __restrict__ pooled, float* __restrict__ keysT,
            int Bn, int seg_shift)
{
    const int nseg = 1 << seg_shift;
    const int b = blockIdx.x, d = threadIdx.x;
    __shared__ float gb[256];
    __shared__ float pl[128];

    float h[16];
    // s = 0: h0 = 0 -> h = Q, no correction
    float gsum = GS[(size_t)b * 128 + d];
#pragma unroll
    for (int n = 0; n < 16; ++n)
        h[n] = Qg[((size_t)b * 16 + n) * 128 + d];

    for (int s = 1; s < nseg; ++s) {
        const size_t sb = (size_t)s * Bn + b;
        gsum += GS[sb * 128 + d];
        float corr = 0.f;
#pragma unroll
        for (int n = 0; n < 16; ++n) {
            const size_t o = (sb * 16 + n) * 128 + d;
            corr = fmaf(Kg[o], h[n], corr);        // uses pre-update h
            h[n] = fmaf(Pg[o], h[n], Qg[o]);
        }
        gsum += corr;
    }
    float glast = SL[(size_t)b * 128 + d];
#pragma unroll
    for (int n = 0; n < 16; ++n)
        glast = fmaf(CZ[((size_t)b * 16 + n) * 128 + d], h[n], glast);

    gb[d] = gsum * (1.f / (float)L_SEQ);
    gb[128 + d] = glast;
    __syncthreads();
    {
        const int half = d >> 6, oc = d & 63;
        const float* gbp = &gb[half * 128];
        float s = 0.f;
#pragma unroll 16
        for (int i = 0; i < 128; ++i) s = fmaf(gbp[i], out_proj_w[i * 64 + oc], s);
        pooled[(size_t)b * 128 + d] = s;
        pl[d] = s;
    }
    __syncthreads();
    if (d < 64) {
        float s = k_b[d];
#pragma unroll 16
        for (int i = 0; i < 128; ++i) s = fmaf(pl[i], k_w[i * 64 + d], s);
        keysT[(size_t)d * Bn + b] = s;
    }
}

// ---- qk: per query row, q = pooled[idx] @ q_w + q_b ; out = q @ keysT ----
__global__ __launch_bounds__(256)
void qk_kernel(const float* __restrict__ pooled, const int* __restrict__ idx,
               const float* __restrict__ q_w, const float* __restrict__ q_b,
               const float* __restrict__ keysT, float* __restrict__ out, int B)
{
    int n = blockIdx.x, t = threadIdx.x;
    __shared__ float p_lds[128];
    __shared__ float q_lds[64];
    int bi = idx[n];
    if (t < 128) p_lds[t] = pooled[(size_t)bi * 128 + t];
    __syncthreads();
    if (t < 64) {
        float s = q_b[t];
#pragma unroll
        for (int i = 0; i < 128; ++i) s = fmaf(p_lds[i], q_w[i * 64 + t], s);
        q_lds[t] = s;
    }
    __syncthreads();
    for (int m = t; m < B; m += 256) {
        float acc = 0.f;
#pragma unroll
        for (int i = 0; i < 64; ++i) acc = fmaf(q_lds[i], keysT[(size_t)i * B + m], acc);
        out[(size_t)n * B + m] = acc;
    }
}

// ============================ LAUNCH ============================

extern "C" void kernel_launch(void* const* d_in, const int* in_sizes, int n_in,
                              void* d_out, int out_size, void* d_ws, size_t ws_size,
                              hipStream_t stream)
{
    const float* reads      = (const float*)d_in[0];
    const int*   idx        = (const int*)d_in[1];
    const float* exp_w      = (const float*)d_in[2];
    const float* exp_b      = (const float*)d_in[3];
    const float* in_proj_w  = (const float*)d_in[4];
    const float* conv_w     = (const float*)d_in[5];
    const float* conv_b     = (const float*)d_in[6];
    const float* x_proj_w   = (const float*)d_in[7];
    const float* dt_w       = (const float*)d_in[8];
    const float* dt_b       = (const float*)d_in[9];
    const float* A_log      = (const float*)d_in[10];
    const float* D_skip     = (const float*)d_in[11];
    const float* out_proj_w = (const float*)d_in[12];
    const float* q_w        = (const float*)d_in[13];
    const float* q_b        = (const float*)d_in[14];
    const float* k_w        = (const float*)d_in[15];
    const float* k_b        = (const float*)d_in[16];

    const int B = in_sizes[0] / (L_SEQ * 4);
    const int N = in_sizes[1];

    char* wsb = (char*)d_ws;
    size_t off = 0;
    auto alloc = [&](size_t bytes) {
        size_t o = off;
        off = (off + bytes + 255) & ~(size_t)255;
        return o;
    };

    float* pooled = (float*)(wsb + alloc((size_t)B * 128 * 4));
    float* keysT  = (float*)(wsb + alloc((size_t)B * 64 * 4));
    float* weff   = (float*)(wsb + alloc(1024 * 4));
    float* beff   = (float*)(wsb + alloc(256 * 4));
    float* xpwt   = (float*)(wsb + alloc(36 * 132 * 4));

    auto summ_bytes = [&](int shift) {
        size_t rows = ((size_t)B << shift) * 16 * 128;
        return rows * 4 * 3                       // Qg, Pg, Kg
             + ((size_t)B << shift) * 128 * 4     // GS
             + (size_t)B * 16 * 128 * 4           // CZ
             + (size_t)B * 128 * 4 + 8192;        // SL + align slack
    };
    int seg_shift = 3;
    if (off + summ_bytes(3) > ws_size) seg_shift = 2;
    if (off + summ_bytes(2) > ws_size && seg_shift == 2) seg_shift = 0;

    const int nseg = 1 << seg_shift;
    const size_t rows = (size_t)B * nseg * 16 * 128;
    float* Qg = (float*)(wsb + alloc(rows * 4));
    float* Pg = (float*)(wsb + alloc(rows * 4));
    float* Kg = (float*)(wsb + alloc(rows * 4));
    float* GS = (float*)(wsb + alloc((size_t)B * nseg * 128 * 4));
    float* CZ = (float*)(wsb + alloc((size_t)B * 16 * 128 * 4));
    float* SL = (float*)(wsb + alloc((size_t)B * 128 * 4));

    k_prep<<<1, 256, 0, stream>>>(exp_w, exp_b, in_proj_w, x_proj_w, weff, beff, xpwt);
    mamba_seg<<<B * nseg, 256, 0, stream>>>(reads, weff, beff, xpwt, conv_w, conv_b,
                                            dt_w, dt_b, A_log, D_skip,
                                            Qg, Pg, Kg, GS, CZ, SL, B, seg_shift);
    stitch<<<B, 128, 0, stream>>>(Qg, Pg, Kg, GS, CZ, SL, out_proj_w, k_w, k_b,
                                  pooled, keysT, B, seg_shift);
    qk_kernel<<<N, 256, 0, stream>>>(pooled, idx, q_w, q_b, keysT, (float*)d_out, B);
}

// Round 7
// 200.739 us; speedup vs baseline: 1.5082x; 1.3080x over previous
//
#include <hip/hip_runtime.h>
#include <math.h>

#define L_SEQ 256
#define TILE 32

typedef __attribute__((ext_vector_type(2))) float f32x2;

__device__ __forceinline__ f32x2 fma2(f32x2 a, f32x2 b, f32x2 c) {
    return __builtin_elementwise_fma(a, b, c);
}
__device__ __forceinline__ f32x2 splat2(float x) { f32x2 v = {x, x}; return v; }
__device__ __forceinline__ float silu_f(float x) { return x / (1.f + __expf(-x)); }
__device__ __forceinline__ float sp2_f(float x) {
    return log2f(1.f + exp2f(x * 1.44269504f)) * 0.69314718f;
}

// ---- prep: fold exp_w@in_proj_w -> weff/beff ; x_proj_w -> pair-interleaved [18][132] f32x2 ----
__global__ __launch_bounds__(256)
void k_prep(const float* __restrict__ exp_w, const float* __restrict__ exp_b,
            const float* __restrict__ in_proj_w, const float* __restrict__ x_proj_w,
            float* __restrict__ weff, float* __restrict__ beff, float* __restrict__ xpw2f)
{
    const int t = threadIdx.x;
    float a0 = 0, a1 = 0, a2 = 0, a3 = 0, ab = 0;
    for (int k = 0; k < 64; ++k) {
        float w = in_proj_w[k * 256 + t];
        a0 = fmaf(exp_w[k], w, a0);
        a1 = fmaf(exp_w[64 + k], w, a1);
        a2 = fmaf(exp_w[128 + k], w, a2);
        a3 = fmaf(exp_w[192 + k], w, a3);
        ab = fmaf(exp_b[k], w, ab);
    }
    weff[t] = a0; weff[256 + t] = a1; weff[512 + t] = a2; weff[768 + t] = a3;
    beff[t] = ab;
    // xpw2[jg][k] = { W[k][2jg], W[k][2jg+1] }, row stride 132 pairs
    for (int i = t; i < 128 * 36; i += 256) {
        int k = i / 36, j = i - k * 36;
        xpw2f[((j >> 1) * 132 + k) * 2 + (j & 1)] = x_proj_w[i];
    }
}

// ---- segmented fused Mamba: grid = B*NSEG blocks, one (L_SEQ/NSEG)-step segment each ----
template<int NSEG>
__global__ __launch_bounds__(256, 4)
void mamba_seg(const float* __restrict__ reads,
               const float* __restrict__ weff, const float* __restrict__ beff,
               const f32x2* __restrict__ xpw2,
               const float* __restrict__ conv_w, const float* __restrict__ conv_b,
               const float* __restrict__ dt_w, const float* __restrict__ dt_b,
               const float* __restrict__ A_log, const float* __restrict__ D_skip,
               float* __restrict__ Qg, float* __restrict__ Pg, float* __restrict__ Kg,
               float* __restrict__ GS, float* __restrict__ CZ, float* __restrict__ SL,
               int Bn)
{
    constexpr int NTILE_ = (L_SEQ / TILE) / NSEG;
    const int bx = blockIdx.x;
    const int b = bx / NSEG;
    const int sidx = bx - b * NSEG;
    const int seg0 = sidx * NTILE_ * TILE;
    const int t = threadIdx.x;
    const int dA = t & 127, lh = t >> 7;   // phase A/D mapping (channel, l-half)
    const int dd = t >> 1,  g  = t & 1;    // phase E mapping (channel, n-group)

    __shared__ __align__(16) float    RD[2][36 * 4];   // reads rows (+3 halo)
    __shared__ __align__(16) float    XCf[TILE * 132]; // conv output, f32, padded
    __shared__ __align__(16) float    BC[TILE * 32];   // B(16)|C(16) per step
    __shared__ __align__(16) float    DT4[TILE * 4];   // dt-rank outputs
    __shared__ _Float16               ZS[TILE * 128];  // silu(z), fp16
    __shared__ _Float16               DE[TILE * 128];  // delta, fp16

    // phase-E per-lane params (small, persistent)
    const float dskip = D_skip[dd];
    bool structured = true;
#pragma unroll
    for (int k = 0; k < 8; ++k) {
        float a = -__expf(A_log[dd * 16 + g * 8 + k]);
        structured = structured && (fabsf(a + (float)(g * 8 + k + 1)) < 1e-3f);
    }

    const float4* rdv = (const float4*)(reads + (size_t)b * L_SEQ * 4);
    if (t < 35) {
        int row = seg0 - 3 + t;
        float4 v = make_float4(0.f, 0.f, 0.f, 0.f);
        if (row >= 0) v = rdv[row];
        ((float4*)RD[0])[t] = v;
    }

    f32x2 h2[4], P2[4], K2[4];
#pragma unroll
    for (int k = 0; k < 4; ++k) { h2[k] = splat2(0.f); P2[k] = splat2(1.f); K2[k] = splat2(0.f); }
    float gsum = 0.f;

    __syncthreads();

    for (int tile = 0; tile < NTILE_; ++tile) {
        const int cur = tile & 1;
        const int l_off = seg0 + tile * TILE;
        const float4* RDc = (const float4*)RD[cur];

        // ---- phase A: packed (xm,z) GEMV + rolling conv + silu -> XCf, ZS ----
        {
            f32x2 wj0 = {weff[dA],       weff[128 + dA]};
            f32x2 wj1 = {weff[256 + dA], weff[384 + dA]};
            f32x2 wj2 = {weff[512 + dA], weff[640 + dA]};
            f32x2 wj3 = {weff[768 + dA], weff[896 + dA]};
            f32x2 b2  = {beff[dA],       beff[128 + dA]};
            const float4 cw = ((const float4*)conv_w)[dA];
            const float cb = conv_b[dA];
            const int lb = lh * 16;
            float x0, x1, x2;
#pragma unroll
            for (int jj = 0; jj < 3; ++jj) {
                float4 rv = RDc[lb + jj];
                f32x2 xz = fma2(splat2(rv.w), wj3, fma2(splat2(rv.z), wj2,
                           fma2(splat2(rv.y), wj1, fma2(splat2(rv.x), wj0, b2))));
                float v = (l_off + lb - 3 + jj >= 0) ? xz.x : 0.f;
                if (jj == 0) x0 = v; else if (jj == 1) x1 = v; else x2 = v;
            }
#pragma unroll
            for (int i = 0; i < 16; ++i) {
                float4 rv = RDc[lb + 3 + i];
                f32x2 xz = fma2(splat2(rv.w), wj3, fma2(splat2(rv.z), wj2,
                           fma2(splat2(rv.y), wj1, fma2(splat2(rv.x), wj0, b2))));
                float s = cb + x0 * cw.x + x1 * cw.y + x2 * cw.z + xz.x * cw.w;
                XCf[(lb + i) * 132 + dA] = silu_f(s);
                ZS[(lb + i) * 128 + dA] = (_Float16)silu_f(xz.y);
                x0 = x1; x1 = x2; x2 = xz.x;
            }
        }
        __syncthreads();

        // ---- phase C: packed x_proj (32 x 36) -> DT4|BC ; prefetch next RD ----
        if (NTILE_ > 1 && t < 35 && tile + 1 < NTILE_) {
            int row = l_off + TILE - 3 + t;
            ((float4*)RD[cur ^ 1])[t] = rdv[row];
        }
        for (int task = t; task < 288; task += 256) {
            const int lg = task / 18, jg = task - lg * 18;
            const float4* xr0 = (const float4*)&XCf[(2 * lg) * 132];
            const float4* xr1 = (const float4*)&XCf[(2 * lg + 1) * 132];
            const float4* wq  = (const float4*)(xpw2 + (size_t)jg * 132);
            f32x2 a0 = splat2(0.f), a1 = splat2(0.f);
#pragma unroll 8
            for (int kq = 0; kq < 32; ++kq) {
                float4 xa = xr0[kq], xb = xr1[kq];
                float4 qa = wq[2 * kq], qb = wq[2 * kq + 1];
                f32x2 w0 = {qa.x, qa.y}, w1 = {qa.z, qa.w};
                f32x2 w2 = {qb.x, qb.y}, w3 = {qb.z, qb.w};
                a0 = fma2(splat2(xa.x), w0, a0); a1 = fma2(splat2(xb.x), w0, a1);
                a0 = fma2(splat2(xa.y), w1, a0); a1 = fma2(splat2(xb.y), w1, a1);
                a0 = fma2(splat2(xa.z), w2, a0); a1 = fma2(splat2(xb.z), w2, a1);
                a0 = fma2(splat2(xa.w), w3, a0); a1 = fma2(splat2(xb.w), w3, a1);
            }
            const int l = 2 * lg, j = 2 * jg;
            if (j < 4) {
                DT4[l * 4 + j] = a0.x;       DT4[l * 4 + j + 1] = a0.y;
                DT4[(l + 1) * 4 + j] = a1.x; DT4[(l + 1) * 4 + j + 1] = a1.y;
            } else {
                BC[l * 32 + j - 4] = a0.x;       BC[l * 32 + j - 3] = a0.y;
                BC[(l + 1) * 32 + j - 4] = a1.x; BC[(l + 1) * 32 + j - 3] = a1.y;
            }
        }
        __syncthreads();

        // ---- phase D: delta = softplus(dt @ dt_w + dt_b) -> DE ----
        {
            const float dw0 = dt_w[dA], dw1 = dt_w[128 + dA];
            const float dw2 = dt_w[256 + dA], dw3 = dt_w[384 + dA];
            const float db = dt_b[dA];
            const int lb = lh * 16;
#pragma unroll
            for (int i = 0; i < 16; ++i) {
                const int l = lb + i;
                float4 dv = *(const float4*)&DT4[l * 4];
                float dtr = db + dv.x * dw0 + dv.y * dw1 + dv.z * dw2 + dv.w * dw3;
                DE[l * 128 + dA] = (_Float16)sp2_f(dtr);
            }
        }
        __syncthreads();

        // ---- phase E: serial scan, packed f32x2 states (2 lanes x 4 pairs = 16 n) ----
        for (int l = 0; l < TILE; ++l) {
            const float de = (float)DE[l * 128 + dd];
            const float zs = (float)ZS[l * 128 + dd];
            const float xc = XCf[l * 132 + dd];
            const float du = de * xc;
            f32x2 E2[4];
            if (structured) {           // A[n] = -(n+1): e[n] = r^(n+1)
                const float r = exp2f(de * -1.44269504f);
                const float r2 = r * r, r4 = r2 * r2, r8 = r4 * r4;
                const float base = g ? r8 : 1.f;
                E2[0] = (f32x2){r * base, r2 * base};
                const f32x2 r2s = splat2(r2);
                E2[1] = E2[0] * r2s;
                E2[2] = E2[1] * r2s;
                E2[3] = E2[2] * r2s;
            } else {                    // cold generic path (reload A from global)
#pragma unroll
                for (int k = 0; k < 4; ++k) {
                    float e0 = exp2f(de * (-__expf(A_log[dd * 16 + g * 8 + 2 * k])) * 1.44269504f);
                    float e1 = exp2f(de * (-__expf(A_log[dd * 16 + g * 8 + 2 * k + 1])) * 1.44269504f);
                    E2[k] = (f32x2){e0, e1};
                }
            }
            const float4 Bq0 = *(const float4*)&BC[l * 32 + g * 8];
            const float4 Bq1 = *(const float4*)&BC[l * 32 + g * 8 + 4];
            const float4 Cq0 = *(const float4*)&BC[l * 32 + 16 + g * 8];
            const float4 Cq1 = *(const float4*)&BC[l * 32 + 16 + g * 8 + 4];
            const f32x2 B2[4] = {{Bq0.x, Bq0.y}, {Bq0.z, Bq0.w}, {Bq1.x, Bq1.y}, {Bq1.z, Bq1.w}};
            const f32x2 C2[4] = {{Cq0.x, Cq0.y}, {Cq0.z, Cq0.w}, {Cq1.x, Cq1.y}, {Cq1.z, Cq1.w}};
            const f32x2 dus = splat2(du), zss = splat2(zs);
            f32x2 yp2 = splat2(0.f);
#pragma unroll
            for (int k = 0; k < 4; ++k) {
                h2[k] = fma2(E2[k], h2[k], dus * B2[k]);
                yp2 = fma2(h2[k], C2[k], yp2);
                P2[k] = P2[k] * E2[k];
                K2[k] = fma2(zss, C2[k] * P2[k], K2[k]);
            }
            float yp = yp2.x + yp2.y;
            const float y = yp + __shfl_xor(yp, 1);
            gsum += fmaf(xc, dskip, y) * zs;
        }
        __syncthreads();
    }

    // ---- segment summary writeout (LDS still holds last tile) ----
    {
        const float zs_last = (float)ZS[(TILE - 1) * 128 + dd];
        const float xc_last = XCf[(TILE - 1) * 132 + dd];
        const size_t sb = (size_t)sidx * Bn + b;
#pragma unroll
        for (int k = 0; k < 4; ++k) {
            const size_t o = (sb * 16 + g * 8 + 2 * k) * 128 + dd;
            Qg[o] = h2[k].x;  Qg[o + 128] = h2[k].y;
            Pg[o] = P2[k].x;  Pg[o + 128] = P2[k].y;
            Kg[o] = K2[k].x;  Kg[o + 128] = K2[k].y;
        }
        if (g == 0) GS[sb * 128 + dd] = gsum;
        if (sidx == NSEG - 1) {
#pragma unroll
            for (int k = 0; k < 8; ++k)
                CZ[((size_t)b * 16 + g * 8 + k) * 128 + dd] =
                    zs_last * BC[(TILE - 1) * 32 + 16 + g * 8 + k];
            if (g == 0) SL[(size_t)b * 128 + dd] = zs_last * xc_last * dskip;
        }
    }
}

// ---- stitch: chain segment summaries, out_proj, fused keys ----
__global__ __launch_bounds__(128)
void stitch(const float* __restrict__ Qg, const float* __restrict__ Pg,
            const float* __restrict__ Kg, const float* __restrict__ GS,
            const float* __restrict__ CZ, const float* __restrict__ SL,
            const float* __restrict__ out_proj_w,
            const float* __restrict__ k_w, const float* __restrict__ k_b,
            float* __restrict__ pooled, float* __restrict__ keysT,
            int Bn, int nseg)
{
    const int b = blockIdx.x, d = threadIdx.x;
    __shared__ float gb[256];
    __shared__ float pl[128];

    float h[16];
    float gsum = GS[(size_t)b * 128 + d];          // s = 0: h0 = 0
#pragma unroll
    for (int n = 0; n < 16; ++n)
        h[n] = Qg[((size_t)b * 16 + n) * 128 + d];

    for (int s = 1; s < nseg; ++s) {
        const size_t sb = (size_t)s * Bn + b;
        gsum += GS[sb * 128 + d];
        float corr = 0.f;
#pragma unroll
        for (int n = 0; n < 16; ++n) {
            const size_t o = (sb * 16 + n) * 128 + d;
            corr = fmaf(Kg[o], h[n], corr);        // uses pre-update h
            h[n] = fmaf(Pg[o], h[n], Qg[o]);
        }
        gsum += corr;
    }
    float glast = SL[(size_t)b * 128 + d];
#pragma unroll
    for (int n = 0; n < 16; ++n)
        glast = fmaf(CZ[((size_t)b * 16 + n) * 128 + d], h[n], glast);

    gb[d] = gsum * (1.f / (float)L_SEQ);
    gb[128 + d] = glast;
    __syncthreads();
    {
        const int half = d >> 6, oc = d & 63;
        const float* gbp = &gb[half * 128];
        float s = 0.f;
#pragma unroll 16
        for (int i = 0; i < 128; ++i) s = fmaf(gbp[i], out_proj_w[i * 64 + oc], s);
        pooled[(size_t)b * 128 + d] = s;
        pl[d] = s;
    }
    __syncthreads();
    if (d < 64) {
        float s = k_b[d];
#pragma unroll 16
        for (int i = 0; i < 128; ++i) s = fmaf(pl[i], k_w[i * 64 + d], s);
        keysT[(size_t)d * Bn + b] = s;
    }
}

// ---- qk: per query row, q = pooled[idx] @ q_w + q_b ; out = q @ keysT ----
__global__ __launch_bounds__(256)
void qk_kernel(const float* __restrict__ pooled, const int* __restrict__ idx,
               const float* __restrict__ q_w, const float* __restrict__ q_b,
               const float* __restrict__ keysT, float* __restrict__ out, int B)
{
    int n = blockIdx.x, t = threadIdx.x;
    __shared__ float p_lds[128];
    __shared__ float q_lds[64];
    int bi = idx[n];
    if (t < 128) p_lds[t] = pooled[(size_t)bi * 128 + t];
    __syncthreads();
    if (t < 64) {
        float s = q_b[t];
#pragma unroll
        for (int i = 0; i < 128; ++i) s = fmaf(p_lds[i], q_w[i * 64 + t], s);
        q_lds[t] = s;
    }
    __syncthreads();
    for (int m = t; m < B; m += 256) {
        float acc = 0.f;
#pragma unroll
        for (int i = 0; i < 64; ++i) acc = fmaf(q_lds[i], keysT[(size_t)i * B + m], acc);
        out[(size_t)n * B + m] = acc;
    }
}

// ============================ LAUNCH ============================

extern "C" void kernel_launch(void* const* d_in, const int* in_sizes, int n_in,
                              void* d_out, int out_size, void* d_ws, size_t ws_size,
                              hipStream_t stream)
{
    const float* reads      = (const float*)d_in[0];
    const int*   idx        = (const int*)d_in[1];
    const float* exp_w      = (const float*)d_in[2];
    const float* exp_b      = (const float*)d_in[3];
    const float* in_proj_w  = (const float*)d_in[4];
    const float* conv_w     = (const float*)d_in[5];
    const float* conv_b     = (const float*)d_in[6];
    const float* x_proj_w   = (const float*)d_in[7];
    const float* dt_w       = (const float*)d_in[8];
    const float* dt_b       = (const float*)d_in[9];
    const float* A_log      = (const float*)d_in[10];
    const float* D_skip     = (const float*)d_in[11];
    const float* out_proj_w = (const float*)d_in[12];
    const float* q_w        = (const float*)d_in[13];
    const float* q_b        = (const float*)d_in[14];
    const float* k_w        = (const float*)d_in[15];
    const float* k_b        = (const float*)d_in[16];

    const int B = in_sizes[0] / (L_SEQ * 4);
    const int N = in_sizes[1];

    char* wsb = (char*)d_ws;
    size_t off = 0;
    auto alloc = [&](size_t bytes) {
        size_t o = off;
        off = (off + bytes + 255) & ~(size_t)255;
        return o;
    };

    float* pooled = (float*)(wsb + alloc((size_t)B * 128 * 4));
    float* keysT  = (float*)(wsb + alloc((size_t)B * 64 * 4));
    float* weff   = (float*)(wsb + alloc(1024 * 4));
    float* beff   = (float*)(wsb + alloc(256 * 4));
    float* xpw2   = (float*)(wsb + alloc(18 * 132 * 2 * 4));

    auto summ_bytes = [&](int nseg) {
        size_t rows = (size_t)B * nseg * 16 * 128;
        return rows * 4 * 3                       // Qg, Pg, Kg
             + (size_t)B * nseg * 128 * 4         // GS
             + (size_t)B * 16 * 128 * 4           // CZ
             + (size_t)B * 128 * 4 + 8192;        // SL + slack
    };
    const int nseg = (off + summ_bytes(8) <= ws_size) ? 8 : 1;

    const size_t rows = (size_t)B * nseg * 16 * 128;
    float* Qg = (float*)(wsb + alloc(rows * 4));
    float* Pg = (float*)(wsb + alloc(rows * 4));
    float* Kg = (float*)(wsb + alloc(rows * 4));
    float* GS = (float*)(wsb + alloc((size_t)B * nseg * 128 * 4));
    float* CZ = (float*)(wsb + alloc((size_t)B * 16 * 128 * 4));
    float* SL = (float*)(wsb + alloc((size_t)B * 128 * 4));

    k_prep<<<1, 256, 0, stream>>>(exp_w, exp_b, in_proj_w, x_proj_w, weff, beff, xpw2);
    if (nseg == 8) {
        mamba_seg<8><<<B * 8, 256, 0, stream>>>(reads, weff, beff, (const f32x2*)xpw2,
                                                conv_w, conv_b, dt_w, dt_b, A_log, D_skip,
                                                Qg, Pg, Kg, GS, CZ, SL, B);
    } else {
        mamba_seg<1><<<B, 256, 0, stream>>>(reads, weff, beff, (const f32x2*)xpw2,
                                            conv_w, conv_b, dt_w, dt_b, A_log, D_skip,
                                            Qg, Pg, Kg, GS, CZ, SL, B);
    }
    stitch<<<B, 128, 0, stream>>>(Qg, Pg, Kg, GS, CZ, SL, out_proj_w, k_w, k_b,
                                  pooled, keysT, B, nseg);
    qk_kernel<<<N, 256, 0, stream>>>(pooled, idx, q_w, q_b, keysT, (float*)d_out, B);
}

// Round 8
// 179.404 us; speedup vs baseline: 1.6876x; 1.1189x over previous
//
#include <hip/hip_runtime.h>
#include <math.h>

#define L_SEQ 256
#define TILE 32

typedef __attribute__((ext_vector_type(2))) float f32x2;
typedef __attribute__((ext_vector_type(4))) float f32x4;
typedef __attribute__((ext_vector_type(8))) _Float16 f16x8;

__device__ __forceinline__ f32x2 fma2(f32x2 a, f32x2 b, f32x2 c) {
    return __builtin_elementwise_fma(a, b, c);
}
__device__ __forceinline__ f32x2 splat2(float x) { f32x2 v = {x, x}; return v; }
__device__ __forceinline__ float silu_f(float x) { return x / (1.f + __expf(-x)); }
__device__ __forceinline__ float sp2_f(float x) {
    return log2f(1.f + exp2f(x * 1.44269504f)) * 0.69314718f;
}

// ---- prep: weff/beff = exp_w@in_proj_w ; WT[160][128] fp16 = [x_proj[:, :4]@dt_w | x_proj[:,4:36]]^T ----
__global__ __launch_bounds__(256)
void k_prep(const float* __restrict__ exp_w, const float* __restrict__ exp_b,
            const float* __restrict__ in_proj_w, const float* __restrict__ x_proj_w,
            const float* __restrict__ dt_w,
            float* __restrict__ weff, float* __restrict__ beff, _Float16* __restrict__ WT)
{
    const int t = threadIdx.x;
    float a0 = 0, a1 = 0, a2 = 0, a3 = 0, ab = 0;
    for (int k = 0; k < 64; ++k) {
        float w = in_proj_w[k * 256 + t];
        a0 = fmaf(exp_w[k], w, a0);
        a1 = fmaf(exp_w[64 + k], w, a1);
        a2 = fmaf(exp_w[128 + k], w, a2);
        a3 = fmaf(exp_w[192 + k], w, a3);
        ab = fmaf(exp_b[k], w, ab);
    }
    weff[t] = a0; weff[256 + t] = a1; weff[512 + t] = a2; weff[768 + t] = a3;
    beff[t] = ab;
    // WT rows 0..127: (x_proj[:,:4]@dt_w)^T ; rows 128..159: x_proj[:,4+r]^T
    for (int i = t; i < 160 * 128; i += 256) {
        const int row = i >> 7, k = i & 127;
        float v;
        if (row < 128) {
            v = x_proj_w[k * 36 + 0] * dt_w[row]
              + x_proj_w[k * 36 + 1] * dt_w[128 + row]
              + x_proj_w[k * 36 + 2] * dt_w[256 + row]
              + x_proj_w[k * 36 + 3] * dt_w[384 + row];
        } else {
            v = x_proj_w[k * 36 + 4 + (row - 128)];
        }
        WT[i] = (_Float16)v;
    }
}

// ---- segmented fused Mamba: grid = B*NSEG blocks ----
template<int NSEG>
__global__ __launch_bounds__(256, 5)
void mamba_seg(const float* __restrict__ reads,
               const float* __restrict__ weff, const float* __restrict__ beff,
               const _Float16* __restrict__ WT,
               const float* __restrict__ conv_w, const float* __restrict__ conv_b,
               const float* __restrict__ dt_b,
               const float* __restrict__ A_log, const float* __restrict__ D_skip,
               _Float16* __restrict__ Qg, _Float16* __restrict__ Pg, _Float16* __restrict__ Kg,
               float* __restrict__ GS, float* __restrict__ CZ, float* __restrict__ SL,
               int Bn)
{
    constexpr int NTILE_ = (L_SEQ / TILE) / NSEG;
    constexpr int NRD = (NTILE_ > 1) ? 2 : 1;
    const int bx = blockIdx.x;
    const int b = bx / NSEG;
    const int sidx = bx - b * NSEG;
    const int seg0 = sidx * NTILE_ * TILE;
    const int t = threadIdx.x;
    const int dA = t & 127, lh = t >> 7;   // phase A mapping (channel, l-half)
    const int dd = t >> 1,  g  = t & 1;    // phase E mapping (channel, n-group)

    __shared__ __align__(16) float    RD[NRD][36 * 4];  // reads rows (+3 halo)
    __shared__ __align__(16) _Float16 XC[TILE * 136];   // conv output, fp16, padded
    __shared__ __align__(16) float    BC[TILE * 32];    // B(16)|C(16) per step
    __shared__ _Float16               ZS[TILE * 128];   // silu(z), fp16
    __shared__ _Float16               DE[TILE * 128];   // delta, fp16

    // phase-E per-lane params
    const float dskip = D_skip[dd];
    bool structured = true;
#pragma unroll
    for (int k = 0; k < 8; ++k) {
        float a = -__expf(A_log[dd * 16 + g * 8 + k]);
        structured = structured && (fabsf(a + (float)(g * 8 + k + 1)) < 1e-3f);
    }

    const float4* rdv = (const float4*)(reads + (size_t)b * L_SEQ * 4);
    if (t < 35) {
        int row = seg0 - 3 + t;
        float4 v = make_float4(0.f, 0.f, 0.f, 0.f);
        if (row >= 0) v = rdv[row];
        ((float4*)RD[0])[t] = v;
    }

    f32x2 h2[4], P2[4], K2[4];
#pragma unroll
    for (int k = 0; k < 4; ++k) { h2[k] = splat2(0.f); P2[k] = splat2(1.f); K2[k] = splat2(0.f); }
    float gsum = 0.f;

    __syncthreads();

    for (int tile = 0; tile < NTILE_; ++tile) {
        const int cur = (NRD > 1) ? (tile & 1) : 0;
        const int l_off = seg0 + tile * TILE;
        const float4* RDc = (const float4*)RD[cur];

        // ---- phase A: packed (xm,z) GEMV + rolling conv + silu -> XC, ZS ----
        {
            f32x2 wj0 = {weff[dA],       weff[128 + dA]};
            f32x2 wj1 = {weff[256 + dA], weff[384 + dA]};
            f32x2 wj2 = {weff[512 + dA], weff[640 + dA]};
            f32x2 wj3 = {weff[768 + dA], weff[896 + dA]};
            f32x2 b2  = {beff[dA],       beff[128 + dA]};
            const float4 cw = ((const float4*)conv_w)[dA];
            const float cb = conv_b[dA];
            const int lb = lh * 16;
            float x0, x1, x2;
#pragma unroll
            for (int jj = 0; jj < 3; ++jj) {
                float4 rv = RDc[lb + jj];
                f32x2 xz = fma2(splat2(rv.w), wj3, fma2(splat2(rv.z), wj2,
                           fma2(splat2(rv.y), wj1, fma2(splat2(rv.x), wj0, b2))));
                float v = (l_off + lb - 3 + jj >= 0) ? xz.x : 0.f;
                if (jj == 0) x0 = v; else if (jj == 1) x1 = v; else x2 = v;
            }
#pragma unroll
            for (int i = 0; i < 16; ++i) {
                float4 rv = RDc[lb + 3 + i];
                f32x2 xz = fma2(splat2(rv.w), wj3, fma2(splat2(rv.z), wj2,
                           fma2(splat2(rv.y), wj1, fma2(splat2(rv.x), wj0, b2))));
                float s = cb + x0 * cw.x + x1 * cw.y + x2 * cw.z + xz.x * cw.w;
                XC[(lb + i) * 136 + dA] = (_Float16)silu_f(s);
                ZS[(lb + i) * 128 + dA] = (_Float16)silu_f(xz.y);
                x0 = x1; x1 = x2; x2 = xz.x;
            }
        }
        __syncthreads();

        // ---- phase C: MFMA f16 GEMM [32 x 160] = XC[32x128] @ WT^T ----
        // cols 0..127 -> delta_raw (softplus -> DE); cols 128..159 -> B|C -> BC
        {
            if (NTILE_ > 1 && t < 35 && tile + 1 < NTILE_) {   // prefetch next RD
                int row = l_off + TILE - 3 + t;
                ((float4*)RD[cur ^ 1])[t] = rdv[row];
            }
            const int lane = t & 63;
            const int wv = t >> 6;
            const int fcol = lane & 15;
            const int kq = lane >> 4;          // 0..3
            const int rbase = kq * 4;          // D-frag row base
            f32x4 acc[5];
#pragma unroll
            for (int i = 0; i < 5; ++i) acc[i] = (f32x4){0.f, 0.f, 0.f, 0.f};
#pragma unroll
            for (int ks = 0; ks < 4; ++ks) {
                const int ko = ks * 32 + kq * 8;
#pragma unroll
                for (int i = 0; i < 5; ++i) {
                    const int tid = wv * 5 + i;
                    const int m = tid & 1, n = tid >> 1;
                    f16x8 af = *(const f16x8*)&XC[(m * 16 + fcol) * 136 + ko];
                    f16x8 bf = *(const f16x8*)&WT[(n * 16 + fcol) * 128 + ko];
                    acc[i] = __builtin_amdgcn_mfma_f32_16x16x32_f16(af, bf, acc[i], 0, 0, 0);
                }
            }
#pragma unroll
            for (int i = 0; i < 5; ++i) {
                const int tid = wv * 5 + i;
                const int m = tid & 1, n = tid >> 1;
                if (n < 8) {
                    const int ch = n * 16 + fcol;
                    const float db = dt_b[ch];
#pragma unroll
                    for (int r = 0; r < 4; ++r)
                        DE[(m * 16 + rbase + r) * 128 + ch] = (_Float16)sp2_f(acc[i][r] + db);
                } else {
                    const int jb = (n - 8) * 16 + fcol;
#pragma unroll
                    for (int r = 0; r < 4; ++r)
                        BC[(m * 16 + rbase + r) * 32 + jb] = acc[i][r];
                }
            }
        }
        __syncthreads();

        // ---- phase E: serial scan, packed f32x2 states (2 lanes x 4 pairs = 16 n) ----
        {
            auto scan_loop = [&](bool needpk) {
                for (int l = 0; l < TILE; ++l) {
                    const float de = (float)DE[l * 128 + dd];
                    const float zs = (float)ZS[l * 128 + dd];
                    const float xc = (float)XC[l * 136 + dd];
                    const float du = de * xc;
                    f32x2 E2[4];
                    if (structured) {           // A[n] = -(n+1): e[n] = r^(n+1)
                        const float r = exp2f(de * -1.44269504f);
                        const float r2 = r * r, r4 = r2 * r2, r8 = r4 * r4;
                        const float base = g ? r8 : 1.f;
                        E2[0] = (f32x2){r * base, r2 * base};
                        const f32x2 r2s = splat2(r2);
                        E2[1] = E2[0] * r2s;
                        E2[2] = E2[1] * r2s;
                        E2[3] = E2[2] * r2s;
                    } else {                    // cold generic path
#pragma unroll
                        for (int k = 0; k < 4; ++k) {
                            float e0 = exp2f(de * (-__expf(A_log[dd * 16 + g * 8 + 2 * k])) * 1.44269504f);
                            float e1 = exp2f(de * (-__expf(A_log[dd * 16 + g * 8 + 2 * k + 1])) * 1.44269504f);
                            E2[k] = (f32x2){e0, e1};
                        }
                    }
                    const float4 Bq0 = *(const float4*)&BC[l * 32 + g * 8];
                    const float4 Bq1 = *(const float4*)&BC[l * 32 + g * 8 + 4];
                    const float4 Cq0 = *(const float4*)&BC[l * 32 + 16 + g * 8];
                    const float4 Cq1 = *(const float4*)&BC[l * 32 + 16 + g * 8 + 4];
                    const f32x2 B2[4] = {{Bq0.x, Bq0.y}, {Bq0.z, Bq0.w}, {Bq1.x, Bq1.y}, {Bq1.z, Bq1.w}};
                    const f32x2 C2[4] = {{Cq0.x, Cq0.y}, {Cq0.z, Cq0.w}, {Cq1.x, Cq1.y}, {Cq1.z, Cq1.w}};
                    const f32x2 dus = splat2(du), zss = splat2(zs);
                    f32x2 yp2 = splat2(0.f);
#pragma unroll
                    for (int k = 0; k < 4; ++k) {
                        h2[k] = fma2(E2[k], h2[k], dus * B2[k]);
                        yp2 = fma2(h2[k], C2[k], yp2);
                        if (needpk) {
                            P2[k] = P2[k] * E2[k];
                            K2[k] = fma2(zss, C2[k] * P2[k], K2[k]);
                        }
                    }
                    float yp = yp2.x + yp2.y;
                    const float y = yp + __shfl_xor(yp, 1);
                    gsum += fmaf(xc, dskip, y) * zs;
                }
            };
            if (sidx == 0) scan_loop(false);
            else           scan_loop(true);
        }
        __syncthreads();
    }

    // ---- segment summary writeout (LDS still holds last tile) ----
    {
        const float zs_last = (float)ZS[(TILE - 1) * 128 + dd];
        const float xc_last = (float)XC[(TILE - 1) * 136 + dd];
        const size_t sb = (size_t)sidx * Bn + b;
#pragma unroll
        for (int k = 0; k < 4; ++k) {
            const size_t o = (sb * 16 + g * 8 + 2 * k) * 128 + dd;
            Qg[o] = (_Float16)h2[k].x;  Qg[o + 128] = (_Float16)h2[k].y;
            if (sidx != 0) {
                Pg[o] = (_Float16)P2[k].x;  Pg[o + 128] = (_Float16)P2[k].y;
                Kg[o] = (_Float16)K2[k].x;  Kg[o + 128] = (_Float16)K2[k].y;
            }
        }
        if (g == 0) GS[sb * 128 + dd] = gsum;
        if (sidx == NSEG - 1) {
#pragma unroll
            for (int k = 0; k < 8; ++k)
                CZ[((size_t)b * 16 + g * 8 + k) * 128 + dd] =
                    zs_last * BC[(TILE - 1) * 32 + 16 + g * 8 + k];
            if (g == 0) SL[(size_t)b * 128 + dd] = zs_last * xc_last * dskip;
        }
    }
}

// ---- stitch: chain segment summaries, out_proj, fused keys ----
__global__ __launch_bounds__(128)
void stitch(const _Float16* __restrict__ Qg, const _Float16* __restrict__ Pg,
            const _Float16* __restrict__ Kg, const float* __restrict__ GS,
            const float* __restrict__ CZ, const float* __restrict__ SL,
            const float* __restrict__ out_proj_w,
            const float* __restrict__ k_w, const float* __restrict__ k_b,
            float* __restrict__ pooled, float* __restrict__ keysT,
            int Bn, int nseg)
{
    const int b = blockIdx.x, d = threadIdx.x;
    __shared__ float gb[256];
    __shared__ float pl[128];

    float h[16];
    float gsum = GS[(size_t)b * 128 + d];          // s = 0: h0 = 0
#pragma unroll
    for (int n = 0; n < 16; ++n)
        h[n] = (float)Qg[((size_t)b * 16 + n) * 128 + d];

    for (int s = 1; s < nseg; ++s) {
        const size_t sb = (size_t)s * Bn + b;
        gsum += GS[sb * 128 + d];
        float corr = 0.f;
#pragma unroll
        for (int n = 0; n < 16; ++n) {
            const size_t o = (sb * 16 + n) * 128 + d;
            corr = fmaf((float)Kg[o], h[n], corr);         // uses pre-update h
            h[n] = fmaf((float)Pg[o], h[n], (float)Qg[o]);
        }
        gsum += corr;
    }
    float glast = SL[(size_t)b * 128 + d];
#pragma unroll
    for (int n = 0; n < 16; ++n)
        glast = fmaf(CZ[((size_t)b * 16 + n) * 128 + d], h[n], glast);

    gb[d] = gsum * (1.f / (float)L_SEQ);
    gb[128 + d] = glast;
    __syncthreads();
    {
        const int half = d >> 6, oc = d & 63;
        const float* gbp = &gb[half * 128];
        float s = 0.f;
#pragma unroll 16
        for (int i = 0; i < 128; ++i) s = fmaf(gbp[i], out_proj_w[i * 64 + oc], s);
        pooled[(size_t)b * 128 + d] = s;
        pl[d] = s;
    }
    __syncthreads();
    if (d < 64) {
        float s = k_b[d];
#pragma unroll 16
        for (int i = 0; i < 128; ++i) s = fmaf(pl[i], k_w[i * 64 + d], s);
        keysT[(size_t)d * Bn + b] = s;
    }
}

// ---- qk: per query row, q = pooled[idx] @ q_w + q_b ; out = q @ keysT ----
__global__ __launch_bounds__(256)
void qk_kernel(const float* __restrict__ pooled, const int* __restrict__ idx,
               const float* __restrict__ q_w, const float* __restrict__ q_b,
               const float* __restrict__ keysT, float* __restrict__ out, int B)
{
    int n = blockIdx.x, t = threadIdx.x;
    __shared__ float p_lds[128];
    __shared__ float q_lds[64];
    int bi = idx[n];
    if (t < 128) p_lds[t] = pooled[(size_t)bi * 128 + t];
    __syncthreads();
    if (t < 64) {
        float s = q_b[t];
#pragma unroll
        for (int i = 0; i < 128; ++i) s = fmaf(p_lds[i], q_w[i * 64 + t], s);
        q_lds[t] = s;
    }
    __syncthreads();
    for (int m = t; m < B; m += 256) {
        float acc = 0.f;
#pragma unroll
        for (int i = 0; i < 64; ++i) acc = fmaf(q_lds[i], keysT[(size_t)i * B + m], acc);
        out[(size_t)n * B + m] = acc;
    }
}

// ============================ LAUNCH ============================

extern "C" void kernel_launch(void* const* d_in, const int* in_sizes, int n_in,
                              void* d_out, int out_size, void* d_ws, size_t ws_size,
                              hipStream_t stream)
{
    const float* reads      = (const float*)d_in[0];
    const int*   idx        = (const int*)d_in[1];
    const float* exp_w      = (const float*)d_in[2];
    const float* exp_b      = (const float*)d_in[3];
    const float* in_proj_w  = (const float*)d_in[4];
    const float* conv_w     = (const float*)d_in[5];
    const float* conv_b     = (const float*)d_in[6];
    const float* x_proj_w   = (const float*)d_in[7];
    const float* dt_w       = (const float*)d_in[8];
    const float* dt_b       = (const float*)d_in[9];
    const float* A_log      = (const float*)d_in[10];
    const float* D_skip     = (const float*)d_in[11];
    const float* out_proj_w = (const float*)d_in[12];
    const float* q_w        = (const float*)d_in[13];
    const float* q_b        = (const float*)d_in[14];
    const float* k_w        = (const float*)d_in[15];
    const float* k_b        = (const float*)d_in[16];

    const int B = in_sizes[0] / (L_SEQ * 4);
    const int N = in_sizes[1];

    char* wsb = (char*)d_ws;
    size_t off = 0;
    auto alloc = [&](size_t bytes) {
        size_t o = off;
        off = (off + bytes + 255) & ~(size_t)255;
        return o;
    };

    float*     pooled = (float*)(wsb + alloc((size_t)B * 128 * 4));
    float*     keysT  = (float*)(wsb + alloc((size_t)B * 64 * 4));
    float*     weff   = (float*)(wsb + alloc(1024 * 4));
    float*     beff   = (float*)(wsb + alloc(256 * 4));
    _Float16*  WT     = (_Float16*)(wsb + alloc(160 * 128 * 2));

    auto summ_bytes = [&](int nseg) {
        size_t rows = (size_t)B * nseg * 16 * 128;
        return rows * 2 * 3                       // Qg, Pg, Kg (fp16)
             + (size_t)B * nseg * 128 * 4         // GS
             + (size_t)B * 16 * 128 * 4           // CZ
             + (size_t)B * 128 * 4 + 8192;        // SL + slack
    };
    const int nseg = (off + summ_bytes(8) <= ws_size) ? 8 : 1;

    const size_t rows = (size_t)B * nseg * 16 * 128;
    _Float16* Qg = (_Float16*)(wsb + alloc(rows * 2));
    _Float16* Pg = (_Float16*)(wsb + alloc(rows * 2));
    _Float16* Kg = (_Float16*)(wsb + alloc(rows * 2));
    float*    GS = (float*)(wsb + alloc((size_t)B * nseg * 128 * 4));
    float*    CZ = (float*)(wsb + alloc((size_t)B * 16 * 128 * 4));
    float*    SL = (float*)(wsb + alloc((size_t)B * 128 * 4));

    k_prep<<<1, 256, 0, stream>>>(exp_w, exp_b, in_proj_w, x_proj_w, dt_w,
                                  weff, beff, WT);
    if (nseg == 8) {
        mamba_seg<8><<<B * 8, 256, 0, stream>>>(reads, weff, beff, WT,
                                                conv_w, conv_b, dt_b, A_log, D_skip,
                                                Qg, Pg, Kg, GS, CZ, SL, B);
    } else {
        mamba_seg<1><<<B, 256, 0, stream>>>(reads, weff, beff, WT,
                                            conv_w, conv_b, dt_b, A_log, D_skip,
                                            Qg, Pg, Kg, GS, CZ, SL, B);
    }
    stitch<<<B, 128, 0, stream>>>(Qg, Pg, Kg, GS, CZ, SL, out_proj_w, k_w, k_b,
                                  pooled, keysT, B, nseg);
    qk_kernel<<<N, 256, 0, stream>>>(pooled, idx, q_w, q_b, keysT, (float*)d_out, B);
}

// Round 9
// 144.097 us; speedup vs baseline: 2.1011x; 1.2450x over previous
//
#include <hip/hip_runtime.h>
#include <math.h>

#define L_SEQ 256
#define TILE 32

typedef __attribute__((ext_vector_type(2))) float f32x2;
typedef __attribute__((ext_vector_type(4))) float f32x4;
typedef __attribute__((ext_vector_type(8))) _Float16 f16x8;
typedef __attribute__((ext_vector_type(2))) _Float16 f16x2;

__device__ __forceinline__ f32x2 fma2(f32x2 a, f32x2 b, f32x2 c) {
    return __builtin_elementwise_fma(a, b, c);
}
__device__ __forceinline__ f32x2 splat2(float x) { f32x2 v = {x, x}; return v; }
__device__ __forceinline__ float silu_f(float x) { return x / (1.f + __expf(-x)); }
__device__ __forceinline__ float sp2_f(float x) {
    return log2f(1.f + exp2f(x * 1.44269504f)) * 0.69314718f;
}

// ---- prep (6 blocks): b0 -> weff/beff ; b1..5 -> WT[160][128] fp16 ----
__global__ __launch_bounds__(256)
void k_prep(const float* __restrict__ exp_w, const float* __restrict__ exp_b,
            const float* __restrict__ in_proj_w, const float* __restrict__ x_proj_w,
            const float* __restrict__ dt_w,
            float* __restrict__ weff, float* __restrict__ beff, _Float16* __restrict__ WT)
{
    const int t = threadIdx.x;
    if (blockIdx.x == 0) {
        float a0 = 0, a1 = 0, a2 = 0, a3 = 0, ab = 0;
        for (int k = 0; k < 64; ++k) {
            float w = in_proj_w[k * 256 + t];
            a0 = fmaf(exp_w[k], w, a0);
            a1 = fmaf(exp_w[64 + k], w, a1);
            a2 = fmaf(exp_w[128 + k], w, a2);
            a3 = fmaf(exp_w[192 + k], w, a3);
            ab = fmaf(exp_b[k], w, ab);
        }
        weff[t] = a0; weff[256 + t] = a1; weff[512 + t] = a2; weff[768 + t] = a3;
        beff[t] = ab;
    } else {
        // WT rows 0..127: (x_proj[:,:4]@dt_w)^T ; rows 128..159: x_proj[:,4+r]^T
        const int base = (blockIdx.x - 1) * 4096;
        for (int i = base + t; i < base + 4096; i += 256) {
            const int row = i >> 7, k = i & 127;
            float v;
            if (row < 128) {
                v = x_proj_w[k * 36 + 0] * dt_w[row]
                  + x_proj_w[k * 36 + 1] * dt_w[128 + row]
                  + x_proj_w[k * 36 + 2] * dt_w[256 + row]
                  + x_proj_w[k * 36 + 3] * dt_w[384 + row];
            } else {
                v = x_proj_w[k * 36 + 4 + (row - 128)];
            }
            WT[i] = (_Float16)v;
        }
    }
}

// ---- segmented fused Mamba: grid = B*NSEG blocks x 512 threads ----
template<int NSEG>
__global__ __launch_bounds__(512, 8)
void mamba_seg(const float* __restrict__ reads,
               const float* __restrict__ weff, const float* __restrict__ beff,
               const _Float16* __restrict__ WT,
               const float* __restrict__ conv_w, const float* __restrict__ conv_b,
               const float* __restrict__ dt_b,
               const float* __restrict__ A_log, const float* __restrict__ D_skip,
               f16x2* __restrict__ Qg, f16x2* __restrict__ Pg, f16x2* __restrict__ Kg,
               float* __restrict__ GS, float* __restrict__ CZ, float* __restrict__ SL,
               int Bn)
{
    constexpr int NTILE_ = (L_SEQ / TILE) / NSEG;
    constexpr int NRD = (NTILE_ > 1) ? 2 : 1;
    const int bx = blockIdx.x;
    const int b = bx / NSEG;
    const int sidx = bx - b * NSEG;
    const int seg0 = sidx * NTILE_ * TILE;
    const int t = threadIdx.x;
    const int dA = t & 127, lh = t >> 7;   // phase A: channel, step-quarter
    const int dd = t >> 2,  g  = t & 3;    // phase E: channel, state-quad

    __shared__ __align__(16) float    RD[NRD][36 * 4];  // reads rows (+3 halo)
    __shared__ __align__(16) _Float16 XC[TILE * 136];   // conv output, fp16, padded
    __shared__ __align__(16) float    BC[TILE * 32];    // B(16)|C(16) per step
    __shared__ _Float16               ZS[TILE * 128];   // silu(z), fp16
    __shared__ _Float16               DE[TILE * 128];   // delta, fp16

    // phase-E per-lane params
    const float dskip = D_skip[dd];
    const float c1 = -1.44269504f * (float)(4 * g + 1);   // r^(4g+1) exponent scale
    bool structured = true;
#pragma unroll
    for (int k = 0; k < 4; ++k) {
        float a = -__expf(A_log[dd * 16 + g * 4 + k]);
        structured = structured && (fabsf(a + (float)(g * 4 + k + 1)) < 1e-3f);
    }

    const float4* rdv = (const float4*)(reads + (size_t)b * L_SEQ * 4);
    if (t < 35) {
        int row = seg0 - 3 + t;
        float4 v = make_float4(0.f, 0.f, 0.f, 0.f);
        if (row >= 0) v = rdv[row];
        ((float4*)RD[0])[t] = v;
    }

    f32x2 h2[2], P2[2], K2[2];
#pragma unroll
    for (int k = 0; k < 2; ++k) { h2[k] = splat2(0.f); P2[k] = splat2(1.f); K2[k] = splat2(0.f); }
    float gsum = 0.f;

    __syncthreads();

    for (int tile = 0; tile < NTILE_; ++tile) {
        const int cur = (NRD > 1) ? (tile & 1) : 0;
        const int l_off = seg0 + tile * TILE;
        const float4* RDc = (const float4*)RD[cur];

        // ---- phase A: packed (xm,z) GEMV + rolling conv + silu -> XC, ZS ----
        {
            f32x2 wj0 = {weff[dA],       weff[128 + dA]};
            f32x2 wj1 = {weff[256 + dA], weff[384 + dA]};
            f32x2 wj2 = {weff[512 + dA], weff[640 + dA]};
            f32x2 b2  = {beff[dA],       beff[128 + dA]};
            f32x2 wj3 = {weff[768 + dA], weff[896 + dA]};
            const float4 cw = ((const float4*)conv_w)[dA];
            const float cb = conv_b[dA];
            const int lb = lh * 8;
            float x0, x1, x2;
#pragma unroll
            for (int jj = 0; jj < 3; ++jj) {
                float4 rv = RDc[lb + jj];
                f32x2 xz = fma2(splat2(rv.w), wj3, fma2(splat2(rv.z), wj2,
                           fma2(splat2(rv.y), wj1, fma2(splat2(rv.x), wj0, b2))));
                float v = (l_off + lb - 3 + jj >= 0) ? xz.x : 0.f;
                if (jj == 0) x0 = v; else if (jj == 1) x1 = v; else x2 = v;
            }
#pragma unroll
            for (int i = 0; i < 8; ++i) {
                float4 rv = RDc[lb + 3 + i];
                f32x2 xz = fma2(splat2(rv.w), wj3, fma2(splat2(rv.z), wj2,
                           fma2(splat2(rv.y), wj1, fma2(splat2(rv.x), wj0, b2))));
                float s = cb + x0 * cw.x + x1 * cw.y + x2 * cw.z + xz.x * cw.w;
                XC[(lb + i) * 136 + dA] = (_Float16)silu_f(s);
                ZS[(lb + i) * 128 + dA] = (_Float16)silu_f(xz.y);
                x0 = x1; x1 = x2; x2 = xz.x;
            }
        }
        __syncthreads();

        // ---- phase C: MFMA f16 GEMM [32 x 160] = XC[32x128] @ WT^T ----
        // cols 0..127 -> delta_raw (softplus -> DE); cols 128..159 -> B|C -> BC
        {
            if (NTILE_ > 1 && t < 35 && tile + 1 < NTILE_) {   // prefetch next RD
                int row = l_off + TILE - 3 + t;
                ((float4*)RD[cur ^ 1])[t] = rdv[row];
            }
            const int lane = t & 63;
            const int wv = t >> 6;             // 0..7
            const int fcol = lane & 15;
            const int kq = lane >> 4;          // 0..3
            const int rbase = kq * 4;          // D-frag row base
#pragma unroll
            for (int i = 0; i < 3; ++i) {
                const int tid = wv + 8 * i;    // 20 tiles over 8 waves
                if (tid >= 20) break;
                const int m = tid & 1, n = tid >> 1;
                f32x4 acc = {0.f, 0.f, 0.f, 0.f};
#pragma unroll
                for (int ks = 0; ks < 4; ++ks) {
                    const int ko = ks * 32 + kq * 8;
                    f16x8 af = *(const f16x8*)&XC[(m * 16 + fcol) * 136 + ko];
                    f16x8 bf = *(const f16x8*)&WT[(n * 16 + fcol) * 128 + ko];
                    acc = __builtin_amdgcn_mfma_f32_16x16x32_f16(af, bf, acc, 0, 0, 0);
                }
                if (n < 8) {
                    const int ch = n * 16 + fcol;
                    const float db = dt_b[ch];
#pragma unroll
                    for (int r = 0; r < 4; ++r)
                        DE[(m * 16 + rbase + r) * 128 + ch] = (_Float16)sp2_f(acc[r] + db);
                } else {
                    const int jb = (n - 8) * 16 + fcol;
#pragma unroll
                    for (int r = 0; r < 4; ++r)
                        BC[(m * 16 + rbase + r) * 32 + jb] = acc[r];
                }
            }
        }
        __syncthreads();

        // ---- phase E: serial scan; 4 lanes/channel, 4 states each (2 f32x2) ----
        {
            auto scan_loop = [&](bool needpk) {
                for (int l = 0; l < TILE; ++l) {
                    const float de = (float)DE[l * 128 + dd];
                    const float zs = (float)ZS[l * 128 + dd];
                    const float xc = (float)XC[l * 136 + dd];
                    const float du = de * xc;
                    f32x2 E2[2];
                    if (structured) {          // states 4g+1..4g+4: r^(4g+1)..r^(4g+4)
                        const float r  = exp2f(de * -1.44269504f);
                        const float t1 = exp2f(de * c1);        // r^(4g+1)
                        const float r2 = r * r;
                        E2[0] = (f32x2){t1, t1 * r};
                        E2[1] = E2[0] * splat2(r2);
                    } else {                   // cold generic path
#pragma unroll
                        for (int k = 0; k < 2; ++k) {
                            float e0 = exp2f(de * (-__expf(A_log[dd * 16 + g * 4 + 2 * k])) * 1.44269504f);
                            float e1 = exp2f(de * (-__expf(A_log[dd * 16 + g * 4 + 2 * k + 1])) * 1.44269504f);
                            E2[k] = (f32x2){e0, e1};
                        }
                    }
                    const float4 Bq = *(const float4*)&BC[l * 32 + g * 4];
                    const float4 Cq = *(const float4*)&BC[l * 32 + 16 + g * 4];
                    const f32x2 B2[2] = {{Bq.x, Bq.y}, {Bq.z, Bq.w}};
                    const f32x2 C2[2] = {{Cq.x, Cq.y}, {Cq.z, Cq.w}};
                    const f32x2 dus = splat2(du), zss = splat2(zs);
                    f32x2 yp2 = splat2(0.f);
#pragma unroll
                    for (int k = 0; k < 2; ++k) {
                        h2[k] = fma2(E2[k], h2[k], dus * B2[k]);
                        yp2 = fma2(h2[k], C2[k], yp2);
                        if (needpk) {
                            P2[k] = P2[k] * E2[k];
                            K2[k] = fma2(zss, C2[k] * P2[k], K2[k]);
                        }
                    }
                    float yp = yp2.x + yp2.y;
                    yp += __shfl_xor(yp, 1);
                    yp += __shfl_xor(yp, 2);
                    gsum += fmaf(xc, dskip, yp) * zs;
                }
            };
            if (sidx == 0) scan_loop(false);
            else           scan_loop(true);
        }
        if (NTILE_ > 1) __syncthreads();
    }

    // ---- segment summary writeout (LDS still holds last tile) ----
    {
        const float zs_last = (float)ZS[(TILE - 1) * 128 + dd];
        const float xc_last = (float)XC[(TILE - 1) * 136 + dd];
        const size_t sb = (size_t)sidx * Bn + b;
#pragma unroll
        for (int k = 0; k < 2; ++k) {
            const size_t o = (sb * 8 + g * 2 + k) * 128 + dd;   // pair p = g*2+k
            Qg[o] = (f16x2){(_Float16)h2[k].x, (_Float16)h2[k].y};
            if (sidx != 0) {
                Pg[o] = (f16x2){(_Float16)P2[k].x, (_Float16)P2[k].y};
                Kg[o] = (f16x2){(_Float16)K2[k].x, (_Float16)K2[k].y};
            }
        }
        if (g == 0) GS[sb * 128 + dd] = gsum;
        if (sidx == NSEG - 1) {
#pragma unroll
            for (int k = 0; k < 4; ++k)
                CZ[((size_t)b * 16 + g * 4 + k) * 128 + dd] =
                    zs_last * BC[(TILE - 1) * 32 + 16 + g * 4 + k];
            if (g == 0) SL[(size_t)b * 128 + dd] = zs_last * xc_last * dskip;
        }
    }
}

// ---- stitch: chain segment summaries, out_proj, fused keys ----
template<int NS>
__global__ __launch_bounds__(128)
void stitch(const f16x2* __restrict__ Qg, const f16x2* __restrict__ Pg,
            const f16x2* __restrict__ Kg, const float* __restrict__ GS,
            const float* __restrict__ CZ, const float* __restrict__ SL,
            const float* __restrict__ out_proj_w,
            const float* __restrict__ k_w, const float* __restrict__ k_b,
            float* __restrict__ pooled, float* __restrict__ keysT,
            int Bn)
{
    const int b = blockIdx.x, d = threadIdx.x;
    __shared__ float gb[256];
    __shared__ float pl[128];

    float h[16];
    float gsum = GS[(size_t)b * 128 + d];          // s = 0: h0 = 0
#pragma unroll
    for (int p = 0; p < 8; ++p) {
        f16x2 q = Qg[((size_t)b * 8 + p) * 128 + d];
        h[2 * p] = (float)q[0]; h[2 * p + 1] = (float)q[1];
    }
#pragma unroll
    for (int s = 1; s < NS; ++s) {
        const size_t sb = (size_t)s * Bn + b;
        gsum += GS[sb * 128 + d];
        float corr = 0.f;
#pragma unroll
        for (int p = 0; p < 8; ++p) {
            const size_t o = (sb * 8 + p) * 128 + d;
            f16x2 qv = Qg[o], pv = Pg[o], kv = Kg[o];
            corr = fmaf((float)kv[0], h[2 * p], corr);
            corr = fmaf((float)kv[1], h[2 * p + 1], corr);
            h[2 * p]     = fmaf((float)pv[0], h[2 * p],     (float)qv[0]);
            h[2 * p + 1] = fmaf((float)pv[1], h[2 * p + 1], (float)qv[1]);
        }
        gsum += corr;
    }
    float glast = SL[(size_t)b * 128 + d];
#pragma unroll
    for (int n = 0; n < 16; ++n)
        glast = fmaf(CZ[((size_t)b * 16 + n) * 128 + d], h[n], glast);

    gb[d] = gsum * (1.f / (float)L_SEQ);
    gb[128 + d] = glast;
    __syncthreads();
    {
        const int half = d >> 6, oc = d & 63;
        const float* gbp = &gb[half * 128];
        float s = 0.f;
#pragma unroll 16
        for (int i = 0; i < 128; ++i) s = fmaf(gbp[i], out_proj_w[i * 64 + oc], s);
        pooled[(size_t)b * 128 + d] = s;
        pl[d] = s;
    }
    __syncthreads();
    if (d < 64) {
        float s = k_b[d];
#pragma unroll 16
        for (int i = 0; i < 128; ++i) s = fmaf(pl[i], k_w[i * 64 + d], s);
        keysT[(size_t)d * Bn + b] = s;
    }
}

// ---- qk: q = pooled[idx[n]] @ q_w + q_b ; out[n, 4t..4t+3] = q @ keysT cols ----
__global__ __launch_bounds__(128)
void qk_kernel(const float* __restrict__ pooled, const int* __restrict__ idx,
               const float* __restrict__ q_w, const float* __restrict__ q_b,
               const float* __restrict__ keysT, float* __restrict__ out, int B)
{
    const int n = blockIdx.x, t = threadIdx.x;
    __shared__ float p_lds[128];
    __shared__ float q_lds[64];
    const int bi = idx[n];
    p_lds[t] = pooled[(size_t)bi * 128 + t];
    __syncthreads();
    if (t < 64) {
        float s = q_b[t];
#pragma unroll
        for (int i = 0; i < 128; ++i) s = fmaf(p_lds[i], q_w[i * 64 + t], s);
        q_lds[t] = s;
    }
    __syncthreads();
    f32x4 acc = {0.f, 0.f, 0.f, 0.f};
    const int m0 = t * 4;
#pragma unroll 8
    for (int i = 0; i < 64; ++i) {
        const float qi = q_lds[i];
        const float4 kv = *(const float4*)&keysT[(size_t)i * B + m0];
        acc[0] = fmaf(qi, kv.x, acc[0]);
        acc[1] = fmaf(qi, kv.y, acc[1]);
        acc[2] = fmaf(qi, kv.z, acc[2]);
        acc[3] = fmaf(qi, kv.w, acc[3]);
    }
    *(f32x4*)&out[(size_t)n * B + m0] = acc;
}

// ============================ LAUNCH ============================

extern "C" void kernel_launch(void* const* d_in, const int* in_sizes, int n_in,
                              void* d_out, int out_size, void* d_ws, size_t ws_size,
                              hipStream_t stream)
{
    const float* reads      = (const float*)d_in[0];
    const int*   idx        = (const int*)d_in[1];
    const float* exp_w      = (const float*)d_in[2];
    const float* exp_b      = (const float*)d_in[3];
    const float* in_proj_w  = (const float*)d_in[4];
    const float* conv_w     = (const float*)d_in[5];
    const float* conv_b     = (const float*)d_in[6];
    const float* x_proj_w   = (const float*)d_in[7];
    const float* dt_w       = (const float*)d_in[8];
    const float* dt_b       = (const float*)d_in[9];
    const float* A_log      = (const float*)d_in[10];
    const float* D_skip     = (const float*)d_in[11];
    const float* out_proj_w = (const float*)d_in[12];
    const float* q_w        = (const float*)d_in[13];
    const float* q_b        = (const float*)d_in[14];
    const float* k_w        = (const float*)d_in[15];
    const float* k_b        = (const float*)d_in[16];

    const int B = in_sizes[0] / (L_SEQ * 4);
    const int N = in_sizes[1];

    char* wsb = (char*)d_ws;
    size_t off = 0;
    auto alloc = [&](size_t bytes) {
        size_t o = off;
        off = (off + bytes + 255) & ~(size_t)255;
        return o;
    };

    float*     pooled = (float*)(wsb + alloc((size_t)B * 128 * 4));
    float*     keysT  = (float*)(wsb + alloc((size_t)B * 64 * 4));
    float*     weff   = (float*)(wsb + alloc(1024 * 4));
    float*     beff   = (float*)(wsb + alloc(256 * 4));
    _Float16*  WT     = (_Float16*)(wsb + alloc(160 * 128 * 2));

    auto summ_bytes = [&](int nseg) {
        size_t pairs = (size_t)B * nseg * 8 * 128;
        return pairs * 4 * 3                      // Qg, Pg, Kg (f16x2)
             + (size_t)B * nseg * 128 * 4         // GS
             + (size_t)B * 16 * 128 * 4           // CZ
             + (size_t)B * 128 * 4 + 8192;        // SL + slack
    };
    const int nseg = (off + summ_bytes(8) <= ws_size) ? 8 : 1;

    const size_t pairs = (size_t)B * nseg * 8 * 128;
    f16x2* Qg = (f16x2*)(wsb + alloc(pairs * 4));
    f16x2* Pg = (f16x2*)(wsb + alloc(pairs * 4));
    f16x2* Kg = (f16x2*)(wsb + alloc(pairs * 4));
    float* GS = (float*)(wsb + alloc((size_t)B * nseg * 128 * 4));
    float* CZ = (float*)(wsb + alloc((size_t)B * 16 * 128 * 4));
    float* SL = (float*)(wsb + alloc((size_t)B * 128 * 4));

    k_prep<<<6, 256, 0, stream>>>(exp_w, exp_b, in_proj_w, x_proj_w, dt_w,
                                  weff, beff, WT);
    if (nseg == 8) {
        mamba_seg<8><<<B * 8, 512, 0, stream>>>(reads, weff, beff, WT,
                                                conv_w, conv_b, dt_b, A_log, D_skip,
                                                Qg, Pg, Kg, GS, CZ, SL, B);
        stitch<8><<<B, 128, 0, stream>>>(Qg, Pg, Kg, GS, CZ, SL, out_proj_w, k_w, k_b,
                                         pooled, keysT, B);
    } else {
        mamba_seg<1><<<B, 512, 0, stream>>>(reads, weff, beff, WT,
                                            conv_w, conv_b, dt_b, A_log, D_skip,
                                            Qg, Pg, Kg, GS, CZ, SL, B);
        stitch<1><<<B, 128, 0, stream>>>(Qg, Pg, Kg, GS, CZ, SL, out_proj_w, k_w, k_b,
                                         pooled, keysT, B);
    }
    qk_kernel<<<N, 128, 0, stream>>>(pooled, idx, q_w, q_b, keysT, (float*)d_out, B);
}

// Round 10
// 140.905 us; speedup vs baseline: 2.1487x; 1.0226x over previous
//
#include <hip/hip_runtime.h>
#include <math.h>

#define L_SEQ 256
#define TILE 32

typedef __attribute__((ext_vector_type(2))) float f32x2;
typedef __attribute__((ext_vector_type(4))) float f32x4;
typedef __attribute__((ext_vector_type(8))) _Float16 f16x8;
typedef __attribute__((ext_vector_type(2))) _Float16 f16x2;

__device__ __forceinline__ f32x2 fma2(f32x2 a, f32x2 b, f32x2 c) {
    return __builtin_elementwise_fma(a, b, c);
}
__device__ __forceinline__ f32x2 splat2(float x) { f32x2 v = {x, x}; return v; }
__device__ __forceinline__ float silu_f(float x) { return x / (1.f + __expf(-x)); }
__device__ __forceinline__ float sp2_f(float x) {
    return log2f(1.f + exp2f(x * 1.44269504f)) * 0.69314718f;
}

// ---- prep1: weff/beff = exp_w @ in_proj_w (cols), exp_b @ in_proj_w ----
__global__ __launch_bounds__(256)
void k_prep1(const float* __restrict__ exp_w, const float* __restrict__ exp_b,
             const float* __restrict__ in_proj_w,
             float* __restrict__ weff, float* __restrict__ beff)
{
    const int t = threadIdx.x;
    float a0 = 0, a1 = 0, a2 = 0, a3 = 0, ab = 0;
    for (int k = 0; k < 64; ++k) {
        float w = in_proj_w[k * 256 + t];
        a0 = fmaf(exp_w[k], w, a0);
        a1 = fmaf(exp_w[64 + k], w, a1);
        a2 = fmaf(exp_w[128 + k], w, a2);
        a3 = fmaf(exp_w[192 + k], w, a3);
        ab = fmaf(exp_b[k], w, ab);
    }
    weff[t] = a0; weff[256 + t] = a1; weff[512 + t] = a2; weff[768 + t] = a3;
    beff[t] = ab;
}

// ---- prep2: WT[160][128] f16 ; W2[256][32] f16 (conv-folded phase-A weights) ; bias2 ----
__global__ __launch_bounds__(256)
void k_prep2(const float* __restrict__ x_proj_w, const float* __restrict__ dt_w,
             const float* __restrict__ conv_w, const float* __restrict__ conv_b,
             const float* __restrict__ weff, const float* __restrict__ beff,
             _Float16* __restrict__ WT, _Float16* __restrict__ W2, float* __restrict__ bias2)
{
    const int t = threadIdx.x;
    const int blk = blockIdx.x;
    if (blk < 5) {
        // WT rows 0..127: (x_proj[:,:4]@dt_w)^T ; rows 128..159: x_proj[:,4+r]^T
        const int base = blk * 4096;
        for (int i = base + t; i < base + 4096; i += 256) {
            const int row = i >> 7, k = i & 127;
            float v;
            if (row < 128) {
                v = x_proj_w[k * 36 + 0] * dt_w[row]
                  + x_proj_w[k * 36 + 1] * dt_w[128 + row]
                  + x_proj_w[k * 36 + 2] * dt_w[256 + row]
                  + x_proj_w[k * 36 + 3] * dt_w[384 + row];
            } else {
                v = x_proj_w[k * 36 + 4 + (row - 128)];
            }
            WT[i] = (_Float16)v;
        }
    } else if (blk == 5) {
        // W2 rows 0..127 (xc channels): j<16 -> cw[k]*wx_c ; 16..19 -> cw[k]*bx ; pad 0
        for (int i = t; i < 128 * 32; i += 256) {
            const int d = i >> 5, j = i & 31;
            float v = 0.f;
            if (j < 16)      v = conv_w[d * 4 + (j >> 2)] * weff[(j & 3) * 256 + d];
            else if (j < 20) v = conv_w[d * 4 + (j - 16)] * beff[d];
            W2[i] = (_Float16)v;
        }
        if (t < 128) bias2[t] = conv_b[t];
    } else {
        // W2 rows 128..255 (z channels): k=3 tap slots carry wz, indicator k=3 carries bz
        for (int i = t; i < 128 * 32; i += 256) {
            const int d = i >> 5, j = i & 31;
            float v = 0.f;
            if (j >= 12 && j < 16) v = weff[(j - 12) * 256 + 128 + d];
            else if (j == 19)      v = beff[128 + d];
            W2[128 * 32 + i] = (_Float16)v;
        }
    }
}

// ---- segmented fused Mamba: grid = B*NSEG blocks x 512 threads ----
template<int NSEG>
__global__ __launch_bounds__(512, 6)
void mamba_seg(const float* __restrict__ reads,
               const _Float16* __restrict__ WT, const _Float16* __restrict__ W2,
               const float* __restrict__ bias2, const float* __restrict__ dt_b,
               const float* __restrict__ A_log, const float* __restrict__ D_skip,
               f16x2* __restrict__ Qg, f16x2* __restrict__ Pg, f16x2* __restrict__ Kg,
               float* __restrict__ GS, float* __restrict__ CZ, float* __restrict__ SL,
               int Bn)
{
    constexpr int NTILE_ = (L_SEQ / TILE) / NSEG;
    const int bx = blockIdx.x;
    const int b = bx / NSEG;
    const int sidx = bx - b * NSEG;
    const int seg0 = sidx * NTILE_ * TILE;
    const int t = threadIdx.x;
    const int dd = t >> 1, g = t & 1;      // phase E: channel, state-half

    __shared__ __align__(16) _Float16 F[32 * 40];     // phase-A features, K-padded
    __shared__ __align__(16) _Float16 XC[TILE * 136]; // conv output, fp16, padded
    __shared__ __align__(16) float    BC[TILE * 32];  // B(16)|C(16) per step
    __shared__ _Float16               ZS[TILE * 128]; // silu(z), fp16
    __shared__ _Float16               DE[TILE * 128]; // delta, fp16

    // phase-E per-lane params (threads t<256 only)
    float dskip = 0.f, c1 = 0.f;
    bool structured = true;
    if (t < 256) {
        dskip = D_skip[dd];
        c1 = -1.44269504f * (float)(8 * g + 1);       // r^(8g+1)
#pragma unroll
        for (int k = 0; k < 8; ++k) {
            float a = -__expf(A_log[dd * 16 + g * 8 + k]);
            structured = structured && (fabsf(a + (float)(g * 8 + k + 1)) < 1e-3f);
        }
    }

    f32x2 h2[4], P2[4], K2[4];
#pragma unroll
    for (int k = 0; k < 4; ++k) { h2[k] = splat2(0.f); P2[k] = splat2(1.f); K2[k] = splat2(0.f); }
    float gsum = 0.f;

    for (int tile = 0; tile < NTILE_; ++tile) {
        const int l_off = seg0 + tile * TILE;

        // ---- build F[32][40]: 16 read-taps + 4 bias indicators + pad ----
        for (int i = t; i < 32 * 40; i += 512) {
            const int l = i / 40, j = i - l * 40;
            _Float16 v = (_Float16)0.f;
            if (j < 16) {
                const int row = l_off + l - 3 + (j >> 2);
                if (row >= 0) v = (_Float16)reads[((size_t)b * L_SEQ + row) * 4 + (j & 3)];
            } else if (j < 20) {
                v = (l_off + l - 3 + (j - 16) >= 0) ? (_Float16)1.f : (_Float16)0.f;
            }
            F[i] = v;
        }
        __syncthreads();

        // ---- phase A: MFMA [32 x 256] = F[32x32] @ W2^T ; epilogue silu -> XC, ZS ----
        {
            const int lane = t & 63, wv = t >> 6;
            const int fcol = lane & 15, kq = lane >> 4, rbase = kq * 4;
#pragma unroll
            for (int i = 0; i < 4; ++i) {
                const int tid = wv + 8 * i;           // 32 tiles over 8 waves
                const int m = tid & 1, n = tid >> 1;
                f16x8 af = *(const f16x8*)&F[(m * 16 + fcol) * 40 + kq * 8];
                f16x8 bf = *(const f16x8*)&W2[(n * 16 + fcol) * 32 + kq * 8];
                f32x4 acc = {0.f, 0.f, 0.f, 0.f};
                acc = __builtin_amdgcn_mfma_f32_16x16x32_f16(af, bf, acc, 0, 0, 0);
                if (n < 8) {
                    const int ch = n * 16 + fcol;
                    const float bv = bias2[ch];
#pragma unroll
                    for (int r = 0; r < 4; ++r)
                        XC[(m * 16 + rbase + r) * 136 + ch] = (_Float16)silu_f(acc[r] + bv);
                } else {
                    const int ch = (n - 8) * 16 + fcol;
#pragma unroll
                    for (int r = 0; r < 4; ++r)
                        ZS[(m * 16 + rbase + r) * 128 + ch] = (_Float16)silu_f(acc[r]);
                }
            }
        }
        __syncthreads();

        // ---- phase C: MFMA [32 x 160] = XC[32x128] @ WT^T -> DE (softplus) | BC ----
        {
            const int lane = t & 63, wv = t >> 6;
            const int fcol = lane & 15, kq = lane >> 4, rbase = kq * 4;
#pragma unroll
            for (int i = 0; i < 3; ++i) {
                const int tid = wv + 8 * i;           // 20 tiles over 8 waves
                if (tid >= 20) break;
                const int m = tid & 1, n = tid >> 1;
                f32x4 acc = {0.f, 0.f, 0.f, 0.f};
#pragma unroll
                for (int ks = 0; ks < 4; ++ks) {
                    const int ko = ks * 32 + kq * 8;
                    f16x8 af = *(const f16x8*)&XC[(m * 16 + fcol) * 136 + ko];
                    f16x8 bf = *(const f16x8*)&WT[(n * 16 + fcol) * 128 + ko];
                    acc = __builtin_amdgcn_mfma_f32_16x16x32_f16(af, bf, acc, 0, 0, 0);
                }
                if (n < 8) {
                    const int ch = n * 16 + fcol;
                    const float db = dt_b[ch];
#pragma unroll
                    for (int r = 0; r < 4; ++r)
                        DE[(m * 16 + rbase + r) * 128 + ch] = (_Float16)sp2_f(acc[r] + db);
                } else {
                    const int jb = (n - 8) * 16 + fcol;
#pragma unroll
                    for (int r = 0; r < 4; ++r)
                        BC[(m * 16 + rbase + r) * 32 + jb] = acc[r];
                }
            }
        }
        __syncthreads();

        // ---- phase E: serial scan; 2 lanes/channel, 8 states each (4 f32x2) ----
        if (t < 256) {
            auto scan_loop = [&](bool needpk) {
                for (int l = 0; l < TILE; ++l) {
                    const float de = (float)DE[l * 128 + dd];
                    const float zs = (float)ZS[l * 128 + dd];
                    const float xc = (float)XC[l * 136 + dd];
                    const float du = de * xc;
                    f32x2 E2[4];
                    if (structured) {          // states 8g+1..8g+8: powers of r
                        const float r = exp2f(de * -1.44269504f);
                        const float t1 = exp2f(de * c1);      // r^(8g+1)
                        const float r2 = r * r;
                        E2[0] = (f32x2){t1, t1 * r};
                        const f32x2 r2s = splat2(r2);
                        E2[1] = E2[0] * r2s;
                        E2[2] = E2[1] * r2s;
                        E2[3] = E2[2] * r2s;
                    } else {                   // cold generic path
#pragma unroll
                        for (int k = 0; k < 4; ++k) {
                            float e0 = exp2f(de * (-__expf(A_log[dd * 16 + g * 8 + 2 * k])) * 1.44269504f);
                            float e1 = exp2f(de * (-__expf(A_log[dd * 16 + g * 8 + 2 * k + 1])) * 1.44269504f);
                            E2[k] = (f32x2){e0, e1};
                        }
                    }
                    const float4 Bq0 = *(const float4*)&BC[l * 32 + g * 8];
                    const float4 Bq1 = *(const float4*)&BC[l * 32 + g * 8 + 4];
                    const float4 Cq0 = *(const float4*)&BC[l * 32 + 16 + g * 8];
                    const float4 Cq1 = *(const float4*)&BC[l * 32 + 16 + g * 8 + 4];
                    const f32x2 B2[4] = {{Bq0.x, Bq0.y}, {Bq0.z, Bq0.w}, {Bq1.x, Bq1.y}, {Bq1.z, Bq1.w}};
                    const f32x2 C2[4] = {{Cq0.x, Cq0.y}, {Cq0.z, Cq0.w}, {Cq1.x, Cq1.y}, {Cq1.z, Cq1.w}};
                    const f32x2 dus = splat2(du), zss = splat2(zs);
                    f32x2 yp2 = splat2(0.f);
#pragma unroll
                    for (int k = 0; k < 4; ++k) {
                        h2[k] = fma2(E2[k], h2[k], dus * B2[k]);
                        yp2 = fma2(h2[k], C2[k], yp2);
                        if (needpk) {
                            P2[k] = P2[k] * E2[k];
                            K2[k] = fma2(zss, C2[k] * P2[k], K2[k]);
                        }
                    }
                    float yp = yp2.x + yp2.y;
                    const float y = yp + __shfl_xor(yp, 1);
                    gsum += fmaf(xc, dskip, y) * zs;
                }
            };
            if (sidx == 0) scan_loop(false);
            else           scan_loop(true);
        }
        if (NTILE_ > 1) __syncthreads();
    }

    // ---- segment summary writeout (LDS still holds last tile) ----
    if (t < 256) {
        const float zs_last = (float)ZS[(TILE - 1) * 128 + dd];
        const float xc_last = (float)XC[(TILE - 1) * 136 + dd];
        const size_t sb = (size_t)sidx * Bn + b;
#pragma unroll
        for (int k = 0; k < 4; ++k) {
            const size_t o = (sb * 8 + g * 4 + k) * 128 + dd;  // pair p=g*4+k -> states 8g+2k,+1
            Qg[o] = (f16x2){(_Float16)h2[k].x, (_Float16)h2[k].y};
            if (sidx != 0) {
                Pg[o] = (f16x2){(_Float16)P2[k].x, (_Float16)P2[k].y};
                Kg[o] = (f16x2){(_Float16)K2[k].x, (_Float16)K2[k].y};
            }
        }
        if (g == 0) GS[sb * 128 + dd] = gsum;
        if (sidx == NSEG - 1) {
#pragma unroll
            for (int k = 0; k < 8; ++k)
                CZ[((size_t)b * 16 + g * 8 + k) * 128 + dd] =
                    zs_last * BC[(TILE - 1) * 32 + 16 + g * 8 + k];
            if (g == 0) SL[(size_t)b * 128 + dd] = zs_last * xc_last * dskip;
        }
    }
}

// ---- stitch: chain segment summaries, out_proj, fused keys ----
template<int NS>
__global__ __launch_bounds__(128)
void stitch(const f16x2* __restrict__ Qg, const f16x2* __restrict__ Pg,
            const f16x2* __restrict__ Kg, const float* __restrict__ GS,
            const float* __restrict__ CZ, const float* __restrict__ SL,
            const float* __restrict__ out_proj_w,
            const float* __restrict__ k_w, const float* __restrict__ k_b,
            float* __restrict__ pooled, float* __restrict__ keysT,
            int Bn)
{
    const int b = blockIdx.x, d = threadIdx.x;
    __shared__ float gb[256];
    __shared__ float pl[128];

    float h[16];
    float gsum = GS[(size_t)b * 128 + d];          // s = 0: h0 = 0
#pragma unroll
    for (int p = 0; p < 8; ++p) {
        f16x2 q = Qg[((size_t)b * 8 + p) * 128 + d];
        h[2 * p] = (float)q[0]; h[2 * p + 1] = (float)q[1];
    }
#pragma unroll
    for (int s = 1; s < NS; ++s) {
        const size_t sb = (size_t)s * Bn + b;
        gsum += GS[sb * 128 + d];
        float corr = 0.f;
#pragma unroll
        for (int p = 0; p < 8; ++p) {
            const size_t o = (sb * 8 + p) * 128 + d;
            f16x2 qv = Qg[o], pv = Pg[o], kv = Kg[o];
            corr = fmaf((float)kv[0], h[2 * p], corr);
            corr = fmaf((float)kv[1], h[2 * p + 1], corr);
            h[2 * p]     = fmaf((float)pv[0], h[2 * p],     (float)qv[0]);
            h[2 * p + 1] = fmaf((float)pv[1], h[2 * p + 1], (float)qv[1]);
        }
        gsum += corr;
    }
    float glast = SL[(size_t)b * 128 + d];
#pragma unroll
    for (int n = 0; n < 16; ++n)
        glast = fmaf(CZ[((size_t)b * 16 + n) * 128 + d], h[n], glast);

    gb[d] = gsum * (1.f / (float)L_SEQ);
    gb[128 + d] = glast;
    __syncthreads();
    {
        const int half = d >> 6, oc = d & 63;
        const float* gbp = &gb[half * 128];
        float s = 0.f;
#pragma unroll 16
        for (int i = 0; i < 128; ++i) s = fmaf(gbp[i], out_proj_w[i * 64 + oc], s);
        pooled[(size_t)b * 128 + d] = s;
        pl[d] = s;
    }
    __syncthreads();
    if (d < 64) {
        float s = k_b[d];
#pragma unroll 16
        for (int i = 0; i < 128; ++i) s = fmaf(pl[i], k_w[i * 64 + d], s);
        keysT[(size_t)d * Bn + b] = s;
    }
}

// ---- qk: q = pooled[idx[n]] @ q_w + q_b ; out[n, 4t..4t+3] = q @ keysT cols ----
__global__ __launch_bounds__(128)
void qk_kernel(const float* __restrict__ pooled, const int* __restrict__ idx,
               const float* __restrict__ q_w, const float* __restrict__ q_b,
               const float* __restrict__ keysT, float* __restrict__ out, int B)
{
    const int n = blockIdx.x, t = threadIdx.x;
    __shared__ float p_lds[128];
    __shared__ float q_lds[64];
    const int bi = idx[n];
    p_lds[t] = pooled[(size_t)bi * 128 + t];
    __syncthreads();
    if (t < 64) {
        float s = q_b[t];
#pragma unroll
        for (int i = 0; i < 128; ++i) s = fmaf(p_lds[i], q_w[i * 64 + t], s);
        q_lds[t] = s;
    }
    __syncthreads();
    f32x4 acc = {0.f, 0.f, 0.f, 0.f};
    const int m0 = t * 4;
#pragma unroll 8
    for (int i = 0; i < 64; ++i) {
        const float qi = q_lds[i];
        const float4 kv = *(const float4*)&keysT[(size_t)i * B + m0];
        acc[0] = fmaf(qi, kv.x, acc[0]);
        acc[1] = fmaf(qi, kv.y, acc[1]);
        acc[2] = fmaf(qi, kv.z, acc[2]);
        acc[3] = fmaf(qi, kv.w, acc[3]);
    }
    *(f32x4*)&out[(size_t)n * B + m0] = acc;
}

// ============================ LAUNCH ============================

extern "C" void kernel_launch(void* const* d_in, const int* in_sizes, int n_in,
                              void* d_out, int out_size, void* d_ws, size_t ws_size,
                              hipStream_t stream)
{
    const float* reads      = (const float*)d_in[0];
    const int*   idx        = (const int*)d_in[1];
    const float* exp_w      = (const float*)d_in[2];
    const float* exp_b      = (const float*)d_in[3];
    const float* in_proj_w  = (const float*)d_in[4];
    const float* conv_w     = (const float*)d_in[5];
    const float* conv_b     = (const float*)d_in[6];
    const float* x_proj_w   = (const float*)d_in[7];
    const float* dt_w       = (const float*)d_in[8];
    const float* dt_b       = (const float*)d_in[9];
    const float* A_log      = (const float*)d_in[10];
    const float* D_skip     = (const float*)d_in[11];
    const float* out_proj_w = (const float*)d_in[12];
    const float* q_w        = (const float*)d_in[13];
    const float* q_b        = (const float*)d_in[14];
    const float* k_w        = (const float*)d_in[15];
    const float* k_b        = (const float*)d_in[16];

    const int B = in_sizes[0] / (L_SEQ * 4);
    const int N = in_sizes[1];

    char* wsb = (char*)d_ws;
    size_t off = 0;
    auto alloc = [&](size_t bytes) {
        size_t o = off;
        off = (off + bytes + 255) & ~(size_t)255;
        return o;
    };

    float*     pooled = (float*)(wsb + alloc((size_t)B * 128 * 4));
    float*     keysT  = (float*)(wsb + alloc((size_t)B * 64 * 4));
    float*     weff   = (float*)(wsb + alloc(1024 * 4));
    float*     beff   = (float*)(wsb + alloc(256 * 4));
    _Float16*  WT     = (_Float16*)(wsb + alloc(160 * 128 * 2));
    _Float16*  W2     = (_Float16*)(wsb + alloc(256 * 32 * 2));
    float*     bias2  = (float*)(wsb + alloc(128 * 4));

    auto summ_bytes = [&](int nseg) {
        size_t pairs = (size_t)B * nseg * 8 * 128;
        return pairs * 4 * 3                      // Qg, Pg, Kg (f16x2)
             + (size_t)B * nseg * 128 * 4         // GS
             + (size_t)B * 16 * 128 * 4           // CZ
             + (size_t)B * 128 * 4 + 8192;        // SL + slack
    };
    const int nseg = (off + summ_bytes(8) <= ws_size) ? 8 : 1;

    const size_t pairs = (size_t)B * nseg * 8 * 128;
    f16x2* Qg = (f16x2*)(wsb + alloc(pairs * 4));
    f16x2* Pg = (f16x2*)(wsb + alloc(pairs * 4));
    f16x2* Kg = (f16x2*)(wsb + alloc(pairs * 4));
    float* GS = (float*)(wsb + alloc((size_t)B * nseg * 128 * 4));
    float* CZ = (float*)(wsb + alloc((size_t)B * 16 * 128 * 4));
    float* SL = (float*)(wsb + alloc((size_t)B * 128 * 4));

    k_prep1<<<1, 256, 0, stream>>>(exp_w, exp_b, in_proj_w, weff, beff);
    k_prep2<<<7, 256, 0, stream>>>(x_proj_w, dt_w, conv_w, conv_b, weff, beff,
                                   WT, W2, bias2);
    if (nseg == 8) {
        mamba_seg<8><<<B * 8, 512, 0, stream>>>(reads, WT, W2, bias2, dt_b,
                                                A_log, D_skip,
                                                Qg, Pg, Kg, GS, CZ, SL, B);
        stitch<8><<<B, 128, 0, stream>>>(Qg, Pg, Kg, GS, CZ, SL, out_proj_w, k_w, k_b,
                                         pooled, keysT, B);
    } else {
        mamba_seg<1><<<B, 512, 0, stream>>>(reads, WT, W2, bias2, dt_b,
                                            A_log, D_skip,
                                            Qg, Pg, Kg, GS, CZ, SL, B);
        stitch<1><<<B, 128, 0, stream>>>(Qg, Pg, Kg, GS, CZ, SL, out_proj_w, k_w, k_b,
                                         pooled, keysT, B);
    }
    qk_kernel<<<N, 128, 0, stream>>>(pooled, idx, q_w, q_b, keysT, (float*)d_out, B);
}